// Round 1
// baseline (2935.433 us; speedup 1.0000x reference)
//
#include <hip/hip_runtime.h>

#define N_NODES 50000
#define N_EDGES 800000
#define F 128
#define BN_EPS 1e-5f
#define SLOPE 0.22916666666666666f  // RReLU eval slope 11/48

// ---------------- scatter: agg[tgt] += w * feat[src] ----------------
// 32 threads per edge, float4 per thread, HW fp32 atomics.
__global__ __launch_bounds__(256) void scatter_k(const float* __restrict__ feat,
        const int* __restrict__ src, const int* __restrict__ tgt,
        const float* __restrict__ ew, float* __restrict__ agg) {
    int t = blockIdx.x * 256 + threadIdx.x;
    int e = t >> 5;
    if (e >= N_EDGES) return;
    int lane = (t & 31) * 4;
    int s = src[e], d = tgt[e];
    float w = ew[e];
    float4 v = *reinterpret_cast<const float4*>(feat + s * F + lane);
    float* o = agg + d * F + lane;
    unsafeAtomicAdd(o + 0, v.x * w);
    unsafeAtomicAdd(o + 1, v.y * w);
    unsafeAtomicAdd(o + 2, v.z * w);
    unsafeAtomicAdd(o + 3, v.w * w);
}

// ------ dual GEMM: out[i][j] = bias[j] + sum_k R[i][k]*Wr[j][k] + T[i][k]*Wt[j][k]
// block = 256 threads, tile = 64 nodes x 128 cols, K processed in 8 chunks of 32
// (4 chunks over R/Wr, 4 over T/Wt). Safe for T == out (block reads only its own
// T rows, all reads precede the epilogue stores).
__global__ __launch_bounds__(256) void gemm_dual(const float* __restrict__ R,
        const float* __restrict__ T, const float* __restrict__ Wr,
        const float* __restrict__ Wt, const float* __restrict__ bias,
        float* __restrict__ out) {
    __shared__ __align__(16) float As[64][36];    // [node][kk], stride 36 (144B, 16B-aligned)
    __shared__ __align__(16) float Bs[32][128];   // [kk][col] transposed weights

    const int tid = threadIdx.x;
    const int tx = tid & 15;      // col group: cols tx*4..+3 and 64+tx*4..+3
    const int ty = tid >> 4;      // node group: nodes ty*4..+3
    const int node0 = blockIdx.x * 64;

    const int ldn = tid >> 3;         // staging node (0..31), +32 second iter
    const int ldf = (tid & 7) * 4;    // staging k offset within chunk

    float acc[4][8];
#pragma unroll
    for (int r = 0; r < 4; ++r)
#pragma unroll
        for (int c = 0; c < 8; ++c) acc[r][c] = 0.f;

    for (int half = 0; half < 2; ++half) {
        const float* IN = half ? T : R;
        const float* W  = half ? Wt : Wr;
        for (int kc = 0; kc < 4; ++kc) {
            const int kb = kc * 32;
            __syncthreads();  // protect LDS reads of previous chunk
            // stage A tile: 64 nodes x 32 k (coalesced float4, transpose-free)
#pragma unroll
            for (int it = 0; it < 2; ++it) {
                int node = ldn + it * 32;
                int row = node0 + node;
                float4 v = make_float4(0.f, 0.f, 0.f, 0.f);
                if (row < N_NODES)
                    v = *reinterpret_cast<const float4*>(IN + row * F + kb + ldf);
                *reinterpret_cast<float4*>(&As[node][ldf]) = v;
            }
            // stage B tile transposed: Bs[kk][j] = W[j][kb+kk]
#pragma unroll
            for (int it = 0; it < 4; ++it) {
                int j = (tid >> 3) + it * 32;
                float4 v = *reinterpret_cast<const float4*>(W + j * F + kb + ldf);
                Bs[ldf + 0][j] = v.x;
                Bs[ldf + 1][j] = v.y;
                Bs[ldf + 2][j] = v.z;
                Bs[ldf + 3][j] = v.w;
            }
            __syncthreads();
#pragma unroll
            for (int kk = 0; kk < 32; ++kk) {
                float a0 = As[ty * 4 + 0][kk];
                float a1 = As[ty * 4 + 1][kk];
                float a2 = As[ty * 4 + 2][kk];
                float a3 = As[ty * 4 + 3][kk];
                float4 b0 = *reinterpret_cast<const float4*>(&Bs[kk][tx * 4]);
                float4 b1 = *reinterpret_cast<const float4*>(&Bs[kk][64 + tx * 4]);
                acc[0][0] += a0 * b0.x; acc[0][1] += a0 * b0.y; acc[0][2] += a0 * b0.z; acc[0][3] += a0 * b0.w;
                acc[0][4] += a0 * b1.x; acc[0][5] += a0 * b1.y; acc[0][6] += a0 * b1.z; acc[0][7] += a0 * b1.w;
                acc[1][0] += a1 * b0.x; acc[1][1] += a1 * b0.y; acc[1][2] += a1 * b0.z; acc[1][3] += a1 * b0.w;
                acc[1][4] += a1 * b1.x; acc[1][5] += a1 * b1.y; acc[1][6] += a1 * b1.z; acc[1][7] += a1 * b1.w;
                acc[2][0] += a2 * b0.x; acc[2][1] += a2 * b0.y; acc[2][2] += a2 * b0.z; acc[2][3] += a2 * b0.w;
                acc[2][4] += a2 * b1.x; acc[2][5] += a2 * b1.y; acc[2][6] += a2 * b1.z; acc[2][7] += a2 * b1.w;
                acc[3][0] += a3 * b0.x; acc[3][1] += a3 * b0.y; acc[3][2] += a3 * b0.z; acc[3][3] += a3 * b0.w;
                acc[3][4] += a3 * b1.x; acc[3][5] += a3 * b1.y; acc[3][6] += a3 * b1.z; acc[3][7] += a3 * b1.w;
            }
        }
    }
    float4 bb0 = *reinterpret_cast<const float4*>(bias + tx * 4);
    float4 bb1 = *reinterpret_cast<const float4*>(bias + 64 + tx * 4);
#pragma unroll
    for (int r = 0; r < 4; ++r) {
        int row = node0 + ty * 4 + r;
        if (row < N_NODES) {
            float4 o0 = make_float4(acc[r][0] + bb0.x, acc[r][1] + bb0.y,
                                    acc[r][2] + bb0.z, acc[r][3] + bb0.w);
            float4 o1 = make_float4(acc[r][4] + bb1.x, acc[r][5] + bb1.y,
                                    acc[r][6] + bb1.z, acc[r][7] + bb1.w);
            *reinterpret_cast<float4*>(out + row * F + tx * 4) = o0;
            *reinterpret_cast<float4*>(out + row * F + 64 + tx * 4) = o1;
        }
    }
}

// ---------------- BN column stats: S[col] = sum h, S2[col] = sum h^2 ----------------
__global__ __launch_bounds__(256) void stats_k(const float* __restrict__ h,
        float* __restrict__ S, float* __restrict__ S2) {
    int col = threadIdx.x & 127;
    int rp = threadIdx.x >> 7;  // 0/1
    float s = 0.f, q = 0.f;
    for (int row = blockIdx.x * 2 + rp; row < N_NODES; row += gridDim.x * 2) {
        float v = h[row * F + col];
        s += v;
        q += v * v;
    }
    __shared__ float ls[256], lq[256];
    ls[threadIdx.x] = s;
    lq[threadIdx.x] = q;
    __syncthreads();
    if (threadIdx.x < 128) {
        s = ls[threadIdx.x] + ls[threadIdx.x + 128];
        q = lq[threadIdx.x] + lq[threadIdx.x + 128];
        unsafeAtomicAdd(&S[col], s);
        unsafeAtomicAdd(&S2[col], q);
    }
}

__global__ void finalize_k(const float* __restrict__ S, const float* __restrict__ S2,
        const float* __restrict__ gamma, const float* __restrict__ beta,
        float* __restrict__ scale, float* __restrict__ shift) {
    int j = threadIdx.x;  // 128 threads
    float mean = S[j] * (1.f / N_NODES);
    float var = S2[j] * (1.f / N_NODES) - mean * mean;
    float inv = rsqrtf(var + BN_EPS);
    float sc = gamma[j] * inv;
    scale[j] = sc;
    shift[j] = beta[j] - mean * sc;
}

// ---------------- normalize + RReLU, in place ----------------
__global__ __launch_bounds__(256) void norm_act_k(float* __restrict__ h,
        const float* __restrict__ scale, const float* __restrict__ shift) {
    int i = blockIdx.x * 256 + threadIdx.x;  // float4 index
    const int n4 = N_NODES * F / 4;
    if (i >= n4) return;
    int cb = (i & 31) * 4;  // column base of this float4
    float4 v = reinterpret_cast<float4*>(h)[i];
    float4 sc = *reinterpret_cast<const float4*>(scale + cb);
    float4 sh = *reinterpret_cast<const float4*>(shift + cb);
    v.x = v.x * sc.x + sh.x;
    v.y = v.y * sc.y + sh.y;
    v.z = v.z * sc.z + sh.z;
    v.w = v.w * sc.w + sh.w;
    v.x = v.x >= 0.f ? v.x : v.x * SLOPE;
    v.y = v.y >= 0.f ? v.y : v.y * SLOPE;
    v.z = v.z >= 0.f ? v.z : v.z * SLOPE;
    v.w = v.w >= 0.f ? v.w : v.w * SLOPE;
    reinterpret_cast<float4*>(h)[i] = v;
}

extern "C" void kernel_launch(void* const* d_in, const int* in_sizes, int n_in,
                              void* d_out, int out_size, void* d_ws, size_t ws_size,
                              hipStream_t stream) {
    const float* x     = (const float*)d_in[0];
    const int*   ei    = (const int*)d_in[1];
    const float* ea    = (const float*)d_in[2];
    const float* W1r   = (const float*)d_in[3];
    const float* b1    = (const float*)d_in[4];
    const float* W1t   = (const float*)d_in[5];
    const float* gamma = (const float*)d_in[6];
    const float* beta  = (const float*)d_in[7];
    const float* W2r   = (const float*)d_in[8];
    const float* b2    = (const float*)d_in[9];
    const float* W2t   = (const float*)d_in[10];
    float* out = (float*)d_out;

    char* ws = (char*)d_ws;
    float* agg   = (float*)ws;                       // 50000*128*4 = 25.6 MB
    float* S     = (float*)(ws + 25600000);          // 128
    float* S2    = S + 128;                          // 128
    float* scale = S + 256;                          // 128
    float* shift = S + 384;                          // 128
    float* h = out;  // h lives in d_out; final gemm overwrites in place (safe, see gemm_dual)

    const int* src = ei;
    const int* tgt = ei + N_EDGES;

    const int gemm_grid = (N_NODES + 63) / 64;       // 782
    const int scat_grid = (N_EDGES * 32) / 256;      // 100000

    // ---- layer 1 ----
    hipMemsetAsync(agg, 0, (size_t)N_NODES * F * 4, stream);
    hipMemsetAsync(S, 0, 2 * 128 * 4, stream);
    scatter_k<<<scat_grid, 256, 0, stream>>>(x, src, tgt, ea, agg);
    gemm_dual<<<gemm_grid, 256, 0, stream>>>(agg, x, W1r, W1t, b1, h);
    // ---- BN + RReLU ----
    stats_k<<<256, 256, 0, stream>>>(h, S, S2);
    finalize_k<<<1, 128, 0, stream>>>(S, S2, gamma, beta, scale, shift);
    norm_act_k<<<(N_NODES * F / 4 + 255) / 256, 256, 0, stream>>>(h, scale, shift);
    // ---- layer 2 ----
    hipMemsetAsync(agg, 0, (size_t)N_NODES * F * 4, stream);
    scatter_k<<<scat_grid, 256, 0, stream>>>(h, src, tgt, ea, agg);
    gemm_dual<<<gemm_grid, 256, 0, stream>>>(agg, h, W2r, W2t, b2, out);
}

// Round 2
// 479.303 us; speedup vs baseline: 6.1244x; 6.1244x over previous
//
#include <hip/hip_runtime.h>

#define N_NODES 50000
#define N_EDGES 800000
#define F 128
#define BN_EPS 1e-5f
#define SLOPE 0.22916666666666666f  // RReLU eval slope 11/48

#define NB ((N_NODES + 255) / 256)  // 196 scan blocks

// ================= CSR build =================
__global__ __launch_bounds__(256) void count_k(const int* __restrict__ tgt,
                                               int* __restrict__ counts) {
    int e = blockIdx.x * 256 + threadIdx.x;
    if (e < N_EDGES) atomicAdd(&counts[tgt[e]], 1);
}

__global__ __launch_bounds__(256) void blocksum_k(const int* __restrict__ counts,
                                                  int* __restrict__ bsum) {
    __shared__ int s[256];
    int i = blockIdx.x * 256 + threadIdx.x;
    int v = (i < N_NODES) ? counts[i] : 0;
    s[threadIdx.x] = v;
    __syncthreads();
    for (int o = 128; o > 0; o >>= 1) {
        if (threadIdx.x < o) s[threadIdx.x] += s[threadIdx.x + o];
        __syncthreads();
    }
    if (threadIdx.x == 0) bsum[blockIdx.x] = s[0];
}

// in-place exclusive scan of bsum[0..nb), nb <= 256, one block
__global__ __launch_bounds__(256) void scanb_k(int* __restrict__ bsum, int nb) {
    __shared__ int s[256];
    int v = (threadIdx.x < nb) ? bsum[threadIdx.x] : 0;
    s[threadIdx.x] = v;
    __syncthreads();
    for (int o = 1; o < 256; o <<= 1) {
        int t = (threadIdx.x >= (unsigned)o) ? s[threadIdx.x - o] : 0;
        __syncthreads();
        s[threadIdx.x] += t;
        __syncthreads();
    }
    if (threadIdx.x < nb) bsum[threadIdx.x] = s[threadIdx.x] - v;  // exclusive
}

__global__ __launch_bounds__(256) void offsets_k(const int* __restrict__ counts,
        const int* __restrict__ bsum, int* __restrict__ offs) {
    __shared__ int s[256];
    int i = blockIdx.x * 256 + threadIdx.x;
    int v = (i < N_NODES) ? counts[i] : 0;
    s[threadIdx.x] = v;
    __syncthreads();
    for (int o = 1; o < 256; o <<= 1) {
        int t = (threadIdx.x >= (unsigned)o) ? s[threadIdx.x - o] : 0;
        __syncthreads();
        s[threadIdx.x] += t;
        __syncthreads();
    }
    int excl = s[threadIdx.x] - v + bsum[blockIdx.x];
    if (i < N_NODES) offs[i] = excl;
    if (i == N_NODES - 1) offs[N_NODES] = excl + v;  // = N_EDGES
}

// recs[p] = {src, weight_bits} sorted by target via per-node cursor
__global__ __launch_bounds__(256) void fill_k(const int* __restrict__ src,
        const int* __restrict__ tgt, const float* __restrict__ ew,
        int* __restrict__ cursor, int2* __restrict__ recs) {
    int e = blockIdx.x * 256 + threadIdx.x;
    if (e >= N_EDGES) return;
    int p = atomicAdd(&cursor[tgt[e]], 1);
    recs[p] = make_int2(src[e], __float_as_int(ew[e]));
}

// ================= gather: agg[n] = sum_{e: tgt=n} w_e * feat[src_e] =================
// one wave per node; lane l owns features [2l, 2l+1]
__global__ __launch_bounds__(256) void gather_k(const float* __restrict__ feat,
        const int* __restrict__ offs, const int2* __restrict__ recs,
        float* __restrict__ agg) {
    int node = blockIdx.x * 4 + (threadIdx.x >> 6);
    if (node >= N_NODES) return;
    int lane = (threadIdx.x & 63) * 2;
    int p = offs[node], end = offs[node + 1];
    float ax = 0.f, ay = 0.f;
    // unroll-by-2 for a little ILP on the dependent rec->row load chain
    for (; p + 1 < end; p += 2) {
        int2 r0 = recs[p];
        int2 r1 = recs[p + 1];
        float2 v0 = *reinterpret_cast<const float2*>(feat + (size_t)r0.x * F + lane);
        float2 v1 = *reinterpret_cast<const float2*>(feat + (size_t)r1.x * F + lane);
        float w0 = __int_as_float(r0.y), w1 = __int_as_float(r1.y);
        ax += w0 * v0.x + w1 * v1.x;
        ay += w0 * v0.y + w1 * v1.y;
    }
    if (p < end) {
        int2 r = recs[p];
        float2 v = *reinterpret_cast<const float2*>(feat + (size_t)r.x * F + lane);
        float w = __int_as_float(r.y);
        ax += w * v.x;
        ay += w * v.y;
    }
    *reinterpret_cast<float2*>(agg + (size_t)node * F + lane) = make_float2(ax, ay);
}

// ====== dual GEMM: out[i][j] = bias[j] + sum_k R[i][k]*Wr[j][k] + T[i][k]*Wt[j][k]
__global__ __launch_bounds__(256) void gemm_dual(const float* __restrict__ R,
        const float* __restrict__ T, const float* __restrict__ Wr,
        const float* __restrict__ Wt, const float* __restrict__ bias,
        float* __restrict__ out) {
    __shared__ __align__(16) float As[64][36];
    __shared__ __align__(16) float Bs[32][128];

    const int tid = threadIdx.x;
    const int tx = tid & 15;
    const int ty = tid >> 4;
    const int node0 = blockIdx.x * 64;

    const int ldn = tid >> 3;
    const int ldf = (tid & 7) * 4;

    float acc[4][8];
#pragma unroll
    for (int r = 0; r < 4; ++r)
#pragma unroll
        for (int c = 0; c < 8; ++c) acc[r][c] = 0.f;

    for (int half = 0; half < 2; ++half) {
        const float* IN = half ? T : R;
        const float* W  = half ? Wt : Wr;
        for (int kc = 0; kc < 4; ++kc) {
            const int kb = kc * 32;
            __syncthreads();
#pragma unroll
            for (int it = 0; it < 2; ++it) {
                int node = ldn + it * 32;
                int row = node0 + node;
                float4 v = make_float4(0.f, 0.f, 0.f, 0.f);
                if (row < N_NODES)
                    v = *reinterpret_cast<const float4*>(IN + row * F + kb + ldf);
                *reinterpret_cast<float4*>(&As[node][ldf]) = v;
            }
#pragma unroll
            for (int it = 0; it < 4; ++it) {
                int j = (tid >> 3) + it * 32;
                float4 v = *reinterpret_cast<const float4*>(W + j * F + kb + ldf);
                Bs[ldf + 0][j] = v.x;
                Bs[ldf + 1][j] = v.y;
                Bs[ldf + 2][j] = v.z;
                Bs[ldf + 3][j] = v.w;
            }
            __syncthreads();
#pragma unroll
            for (int kk = 0; kk < 32; ++kk) {
                float a0 = As[ty * 4 + 0][kk];
                float a1 = As[ty * 4 + 1][kk];
                float a2 = As[ty * 4 + 2][kk];
                float a3 = As[ty * 4 + 3][kk];
                float4 b0 = *reinterpret_cast<const float4*>(&Bs[kk][tx * 4]);
                float4 b1 = *reinterpret_cast<const float4*>(&Bs[kk][64 + tx * 4]);
                acc[0][0] += a0 * b0.x; acc[0][1] += a0 * b0.y; acc[0][2] += a0 * b0.z; acc[0][3] += a0 * b0.w;
                acc[0][4] += a0 * b1.x; acc[0][5] += a0 * b1.y; acc[0][6] += a0 * b1.z; acc[0][7] += a0 * b1.w;
                acc[1][0] += a1 * b0.x; acc[1][1] += a1 * b0.y; acc[1][2] += a1 * b0.z; acc[1][3] += a1 * b0.w;
                acc[1][4] += a1 * b1.x; acc[1][5] += a1 * b1.y; acc[1][6] += a1 * b1.z; acc[1][7] += a1 * b1.w;
                acc[2][0] += a2 * b0.x; acc[2][1] += a2 * b0.y; acc[2][2] += a2 * b0.z; acc[2][3] += a2 * b0.w;
                acc[2][4] += a2 * b1.x; acc[2][5] += a2 * b1.y; acc[2][6] += a2 * b1.z; acc[2][7] += a2 * b1.w;
                acc[3][0] += a3 * b0.x; acc[3][1] += a3 * b0.y; acc[3][2] += a3 * b0.z; acc[3][3] += a3 * b0.w;
                acc[3][4] += a3 * b1.x; acc[3][5] += a3 * b1.y; acc[3][6] += a3 * b1.z; acc[3][7] += a3 * b1.w;
            }
        }
    }
    float4 bb0 = *reinterpret_cast<const float4*>(bias + tx * 4);
    float4 bb1 = *reinterpret_cast<const float4*>(bias + 64 + tx * 4);
#pragma unroll
    for (int r = 0; r < 4; ++r) {
        int row = node0 + ty * 4 + r;
        if (row < N_NODES) {
            float4 o0 = make_float4(acc[r][0] + bb0.x, acc[r][1] + bb0.y,
                                    acc[r][2] + bb0.z, acc[r][3] + bb0.w);
            float4 o1 = make_float4(acc[r][4] + bb1.x, acc[r][5] + bb1.y,
                                    acc[r][6] + bb1.z, acc[r][7] + bb1.w);
            *reinterpret_cast<float4*>(out + row * F + tx * 4) = o0;
            *reinterpret_cast<float4*>(out + row * F + 64 + tx * 4) = o1;
        }
    }
}

// ================= BN stats =================
__global__ __launch_bounds__(256) void stats_k(const float* __restrict__ h,
        float* __restrict__ S, float* __restrict__ S2) {
    int col = threadIdx.x & 127;
    int rp = threadIdx.x >> 7;
    float s = 0.f, q = 0.f;
    for (int row = blockIdx.x * 2 + rp; row < N_NODES; row += gridDim.x * 2) {
        float v = h[row * F + col];
        s += v;
        q += v * v;
    }
    __shared__ float ls[256], lq[256];
    ls[threadIdx.x] = s;
    lq[threadIdx.x] = q;
    __syncthreads();
    if (threadIdx.x < 128) {
        s = ls[threadIdx.x] + ls[threadIdx.x + 128];
        q = lq[threadIdx.x] + lq[threadIdx.x + 128];
        unsafeAtomicAdd(&S[col], s);
        unsafeAtomicAdd(&S2[col], q);
    }
}

__global__ void finalize_k(const float* __restrict__ S, const float* __restrict__ S2,
        const float* __restrict__ gamma, const float* __restrict__ beta,
        float* __restrict__ scale, float* __restrict__ shift) {
    int j = threadIdx.x;
    float mean = S[j] * (1.f / N_NODES);
    float var = S2[j] * (1.f / N_NODES) - mean * mean;
    float inv = rsqrtf(var + BN_EPS);
    float sc = gamma[j] * inv;
    scale[j] = sc;
    shift[j] = beta[j] - mean * sc;
}

__global__ __launch_bounds__(256) void norm_act_k(float* __restrict__ h,
        const float* __restrict__ scale, const float* __restrict__ shift) {
    int i = blockIdx.x * 256 + threadIdx.x;
    const int n4 = N_NODES * F / 4;
    if (i >= n4) return;
    int cb = (i & 31) * 4;
    float4 v = reinterpret_cast<float4*>(h)[i];
    float4 sc = *reinterpret_cast<const float4*>(scale + cb);
    float4 sh = *reinterpret_cast<const float4*>(shift + cb);
    v.x = v.x * sc.x + sh.x;
    v.y = v.y * sc.y + sh.y;
    v.z = v.z * sc.z + sh.z;
    v.w = v.w * sc.w + sh.w;
    v.x = v.x >= 0.f ? v.x : v.x * SLOPE;
    v.y = v.y >= 0.f ? v.y : v.y * SLOPE;
    v.z = v.z >= 0.f ? v.z : v.z * SLOPE;
    v.w = v.w >= 0.f ? v.w : v.w * SLOPE;
    reinterpret_cast<float4*>(h)[i] = v;
}

extern "C" void kernel_launch(void* const* d_in, const int* in_sizes, int n_in,
                              void* d_out, int out_size, void* d_ws, size_t ws_size,
                              hipStream_t stream) {
    const float* x     = (const float*)d_in[0];
    const int*   ei    = (const int*)d_in[1];
    const float* ea    = (const float*)d_in[2];
    const float* W1r   = (const float*)d_in[3];
    const float* b1    = (const float*)d_in[4];
    const float* W1t   = (const float*)d_in[5];
    const float* gamma = (const float*)d_in[6];
    const float* beta  = (const float*)d_in[7];
    const float* W2r   = (const float*)d_in[8];
    const float* b2    = (const float*)d_in[9];
    const float* W2t   = (const float*)d_in[10];
    float* out = (float*)d_out;

    char* ws = (char*)d_ws;
    size_t off = 0;
    float* agg   = (float*)(ws + off); off += (size_t)N_NODES * F * 4;      // 25.6 MB
    int2*  recs  = (int2*)(ws + off);  off += (size_t)N_EDGES * 8;          // 6.4 MB
    int*   counts= (int*)(ws + off);   off += (size_t)N_NODES * 4;
    int*   offs  = (int*)(ws + off);   off += (size_t)(N_NODES + 1) * 4;
    int*   cursor= (int*)(ws + off);   off += (size_t)N_NODES * 4;
    int*   bsum  = (int*)(ws + off);   off += 256 * 4;
    float* S     = (float*)(ws + off); off += 128 * 4;
    float* S2    = (float*)(ws + off); off += 128 * 4;
    float* scale = (float*)(ws + off); off += 128 * 4;
    float* shift = (float*)(ws + off); off += 128 * 4;
    float* h = out;  // h lives in d_out; layer-2 gemm overwrites in place (safe)

    const int* src = ei;
    const int* tgt = ei + N_EDGES;

    const int egrid = (N_EDGES + 255) / 256;
    const int gemm_grid = (N_NODES + 63) / 64;
    const int gath_grid = (N_NODES + 3) / 4;

    // ---- CSR build (once, reused by both layers) ----
    hipMemsetAsync(counts, 0, (size_t)N_NODES * 4, stream);
    hipMemsetAsync(S, 0, 2 * 128 * 4, stream);
    count_k<<<egrid, 256, 0, stream>>>(tgt, counts);
    blocksum_k<<<NB, 256, 0, stream>>>(counts, bsum);
    scanb_k<<<1, 256, 0, stream>>>(bsum, NB);
    offsets_k<<<NB, 256, 0, stream>>>(counts, bsum, offs);
    hipMemcpyAsync(cursor, offs, (size_t)N_NODES * 4, hipMemcpyDeviceToDevice, stream);
    fill_k<<<egrid, 256, 0, stream>>>(src, tgt, ea, cursor, recs);

    // ---- layer 1 ----
    gather_k<<<gath_grid, 256, 0, stream>>>(x, offs, recs, agg);
    gemm_dual<<<gemm_grid, 256, 0, stream>>>(agg, x, W1r, W1t, b1, h);
    // ---- BN + RReLU ----
    stats_k<<<256, 256, 0, stream>>>(h, S, S2);
    finalize_k<<<1, 128, 0, stream>>>(S, S2, gamma, beta, scale, shift);
    norm_act_k<<<(N_NODES * F / 4 + 255) / 256, 256, 0, stream>>>(h, scale, shift);
    // ---- layer 2 ----
    gather_k<<<gath_grid, 256, 0, stream>>>(h, offs, recs, agg);
    gemm_dual<<<gemm_grid, 256, 0, stream>>>(agg, h, W2r, W2t, b2, out);
}

// Round 3
// 332.228 us; speedup vs baseline: 8.8356x; 1.4427x over previous
//
#include <hip/hip_runtime.h>

#define N_NODES 50000
#define N_EDGES 800000
#define F 128
#define BN_EPS 1e-5f
#define SLOPE 0.22916666666666666f  // RReLU eval slope 11/48

#define NB ((N_NODES + 255) / 256)   // 196 scan blocks
#define N_RT (N_NODES / 16)          // 3125 row-tiles (exact)
#define GEMM_GRID 512

typedef __attribute__((ext_vector_type(8))) short bf16x8;
typedef __attribute__((ext_vector_type(4))) float f32x4;

__device__ __forceinline__ float bf2f(ushort u) {
    union { uint i; float f; } v; v.i = (uint)u << 16; return v.f;
}
__device__ __forceinline__ ushort f2bf(float f) {
    union { float f; uint i; } v; v.f = f;
    uint r = v.i + 0x7fffu + ((v.i >> 16) & 1u);  // RNE
    return (ushort)(r >> 16);
}

// ================= CSR build =================
__global__ __launch_bounds__(256) void count_k(const int* __restrict__ tgt,
                                               int* __restrict__ counts) {
    int e = blockIdx.x * 256 + threadIdx.x;
    if (e < N_EDGES) atomicAdd(&counts[tgt[e]], 1);
}

__global__ __launch_bounds__(256) void blocksum_k(const int* __restrict__ counts,
                                                  int* __restrict__ bsum) {
    __shared__ int s[256];
    int i = blockIdx.x * 256 + threadIdx.x;
    int v = (i < N_NODES) ? counts[i] : 0;
    s[threadIdx.x] = v;
    __syncthreads();
    for (int o = 128; o > 0; o >>= 1) {
        if (threadIdx.x < o) s[threadIdx.x] += s[threadIdx.x + o];
        __syncthreads();
    }
    if (threadIdx.x == 0) bsum[blockIdx.x] = s[0];
}

__global__ __launch_bounds__(256) void scanb_k(int* __restrict__ bsum, int nb) {
    __shared__ int s[256];
    int v = (threadIdx.x < nb) ? bsum[threadIdx.x] : 0;
    s[threadIdx.x] = v;
    __syncthreads();
    for (int o = 1; o < 256; o <<= 1) {
        int t = (threadIdx.x >= (unsigned)o) ? s[threadIdx.x - o] : 0;
        __syncthreads();
        s[threadIdx.x] += t;
        __syncthreads();
    }
    if (threadIdx.x < nb) bsum[threadIdx.x] = s[threadIdx.x] - v;  // exclusive
}

__global__ __launch_bounds__(256) void offsets_k(const int* __restrict__ counts,
        const int* __restrict__ bsum, int* __restrict__ offs) {
    __shared__ int s[256];
    int i = blockIdx.x * 256 + threadIdx.x;
    int v = (i < N_NODES) ? counts[i] : 0;
    s[threadIdx.x] = v;
    __syncthreads();
    for (int o = 1; o < 256; o <<= 1) {
        int t = (threadIdx.x >= (unsigned)o) ? s[threadIdx.x - o] : 0;
        __syncthreads();
        s[threadIdx.x] += t;
        __syncthreads();
    }
    int excl = s[threadIdx.x] - v + bsum[blockIdx.x];
    if (i < N_NODES) offs[i] = excl;
    if (i == N_NODES - 1) offs[N_NODES] = excl + v;
}

__global__ __launch_bounds__(256) void fill_k(const int* __restrict__ src,
        const int* __restrict__ tgt, const float* __restrict__ ew,
        int* __restrict__ cursor, int2* __restrict__ recs) {
    int e = blockIdx.x * 256 + threadIdx.x;
    if (e >= N_EDGES) return;
    int p = atomicAdd(&cursor[tgt[e]], 1);
    recs[p] = make_int2(src[e], __float_as_int(ew[e]));
}

// ================= casts to bf16 =================
__global__ __launch_bounds__(256) void castx_k(const float* __restrict__ x,
                                               ushort* __restrict__ xb) {
    int i = blockIdx.x * 256 + threadIdx.x;  // one float4 per thread
    float4 v = reinterpret_cast<const float4*>(x)[i];
    ushort4 o;
    o.x = f2bf(v.x); o.y = f2bf(v.y); o.z = f2bf(v.z); o.w = f2bf(v.w);
    reinterpret_cast<ushort4*>(xb)[i] = o;
}

// converts W1r|W1t|W2r|W2t (each 128x128) into wb back-to-back
__global__ __launch_bounds__(256) void castw_k(const float* __restrict__ W1r,
        const float* __restrict__ W1t, const float* __restrict__ W2r,
        const float* __restrict__ W2t, ushort* __restrict__ wb) {
    int i = blockIdx.x * 256 + threadIdx.x;  // 16384 threads, one float4 each
    int m = i >> 12;                          // 4096 float4 per matrix
    int j = i & 4095;
    const float* srcp = (m == 0) ? W1r : (m == 1) ? W1t : (m == 2) ? W2r : W2t;
    float4 v = reinterpret_cast<const float4*>(srcp)[j];
    ushort4 o;
    o.x = f2bf(v.x); o.y = f2bf(v.y); o.z = f2bf(v.z); o.w = f2bf(v.w);
    reinterpret_cast<ushort4*>(wb)[i] = o;
}

// ================= gather: aggb[n] = sum w_e * featb[src_e]  (bf16 in/out, fp32 accum)
__global__ __launch_bounds__(256) void gather_k(const ushort* __restrict__ feat,
        const int* __restrict__ offs, const int2* __restrict__ recs,
        ushort* __restrict__ agg) {
    int node = blockIdx.x * 4 + (threadIdx.x >> 6);
    int lane2 = (threadIdx.x & 63) * 2;  // bf16 element index
    int p = offs[node], end = offs[node + 1];
    float a0 = 0.f, a1 = 0.f;
    for (; p + 3 < end; p += 4) {
        int2 r0 = recs[p], r1 = recs[p + 1], r2 = recs[p + 2], r3 = recs[p + 3];
        uint u0 = *reinterpret_cast<const uint*>(feat + (size_t)r0.x * F + lane2);
        uint u1 = *reinterpret_cast<const uint*>(feat + (size_t)r1.x * F + lane2);
        uint u2 = *reinterpret_cast<const uint*>(feat + (size_t)r2.x * F + lane2);
        uint u3 = *reinterpret_cast<const uint*>(feat + (size_t)r3.x * F + lane2);
        float w0 = __int_as_float(r0.y), w1 = __int_as_float(r1.y);
        float w2 = __int_as_float(r2.y), w3 = __int_as_float(r3.y);
        a0 += w0 * bf2f((ushort)u0) + w1 * bf2f((ushort)u1)
            + w2 * bf2f((ushort)u2) + w3 * bf2f((ushort)u3);
        a1 += w0 * bf2f((ushort)(u0 >> 16)) + w1 * bf2f((ushort)(u1 >> 16))
            + w2 * bf2f((ushort)(u2 >> 16)) + w3 * bf2f((ushort)(u3 >> 16));
    }
    for (; p < end; ++p) {
        int2 r = recs[p];
        uint u = *reinterpret_cast<const uint*>(feat + (size_t)r.x * F + lane2);
        float w = __int_as_float(r.y);
        a0 += w * bf2f((ushort)u);
        a1 += w * bf2f((ushort)(u >> 16));
    }
    uint o = (uint)f2bf(a0) | ((uint)f2bf(a1) << 16);
    *reinterpret_cast<uint*>(agg + (size_t)node * F + lane2) = o;
}

// ================= MFMA dual GEMM =================
// out[i][j] = bias[j] + sum_k R[i][k]*Wr[j][k] + T[i][k]*Wt[j][k]   (R,T,W bf16; out fp32)
// block = 4 waves; wave w owns cols [w*32, w*32+32); W slice held in registers.
// Grid-strides over 16-row tiles. Optionally accumulates BN column stats into S/S2.
__global__ __launch_bounds__(256) void gemm_mfma(const ushort* __restrict__ R,
        const ushort* __restrict__ T, const ushort* __restrict__ Wr,
        const ushort* __restrict__ Wt, const float* __restrict__ bias,
        float* __restrict__ out, float* __restrict__ S, float* __restrict__ S2,
        int fuse_bn) {
    const int lane = threadIdx.x & 63;
    const int wave = threadIdx.x >> 6;
    const int quad = lane >> 4;
    const int l16 = lane & 15;
    const int cb = wave * 32;

    // B fragments: lane holds W[col][k0..k0+7], col = cb + t*16 + l16, k0 = s*32 + quad*8
    bf16x8 bR[2][4], bT[2][4];
#pragma unroll
    for (int t = 0; t < 2; ++t)
#pragma unroll
        for (int s = 0; s < 4; ++s) {
            int col = cb + t * 16 + l16;
            int k0 = s * 32 + quad * 8;
            bR[t][s] = *reinterpret_cast<const bf16x8*>(Wr + col * F + k0);
            bT[t][s] = *reinterpret_cast<const bf16x8*>(Wt + col * F + k0);
        }
    const float bias0 = bias[cb + l16];
    const float bias1 = bias[cb + 16 + l16];

    float s0 = 0.f, q0 = 0.f, s1 = 0.f, q1 = 0.f;

    for (int rt = blockIdx.x; rt < N_RT; rt += GEMM_GRID) {
        const int row0 = rt * 16;
        const ushort* rA = R + (row0 + l16) * F + quad * 8;
        const ushort* tA = T + (row0 + l16) * F + quad * 8;
        bf16x8 aR0 = *reinterpret_cast<const bf16x8*>(rA);
        bf16x8 aR1 = *reinterpret_cast<const bf16x8*>(rA + 32);
        bf16x8 aR2 = *reinterpret_cast<const bf16x8*>(rA + 64);
        bf16x8 aR3 = *reinterpret_cast<const bf16x8*>(rA + 96);
        bf16x8 aT0 = *reinterpret_cast<const bf16x8*>(tA);
        bf16x8 aT1 = *reinterpret_cast<const bf16x8*>(tA + 32);
        bf16x8 aT2 = *reinterpret_cast<const bf16x8*>(tA + 64);
        bf16x8 aT3 = *reinterpret_cast<const bf16x8*>(tA + 96);

        f32x4 acc0 = {0.f, 0.f, 0.f, 0.f};
        f32x4 acc1 = {0.f, 0.f, 0.f, 0.f};
        acc0 = __builtin_amdgcn_mfma_f32_16x16x32_bf16(aR0, bR[0][0], acc0, 0, 0, 0);
        acc1 = __builtin_amdgcn_mfma_f32_16x16x32_bf16(aR0, bR[1][0], acc1, 0, 0, 0);
        acc0 = __builtin_amdgcn_mfma_f32_16x16x32_bf16(aR1, bR[0][1], acc0, 0, 0, 0);
        acc1 = __builtin_amdgcn_mfma_f32_16x16x32_bf16(aR1, bR[1][1], acc1, 0, 0, 0);
        acc0 = __builtin_amdgcn_mfma_f32_16x16x32_bf16(aR2, bR[0][2], acc0, 0, 0, 0);
        acc1 = __builtin_amdgcn_mfma_f32_16x16x32_bf16(aR2, bR[1][2], acc1, 0, 0, 0);
        acc0 = __builtin_amdgcn_mfma_f32_16x16x32_bf16(aR3, bR[0][3], acc0, 0, 0, 0);
        acc1 = __builtin_amdgcn_mfma_f32_16x16x32_bf16(aR3, bR[1][3], acc1, 0, 0, 0);
        acc0 = __builtin_amdgcn_mfma_f32_16x16x32_bf16(aT0, bT[0][0], acc0, 0, 0, 0);
        acc1 = __builtin_amdgcn_mfma_f32_16x16x32_bf16(aT0, bT[1][0], acc1, 0, 0, 0);
        acc0 = __builtin_amdgcn_mfma_f32_16x16x32_bf16(aT1, bT[0][1], acc0, 0, 0, 0);
        acc1 = __builtin_amdgcn_mfma_f32_16x16x32_bf16(aT1, bT[1][1], acc1, 0, 0, 0);
        acc0 = __builtin_amdgcn_mfma_f32_16x16x32_bf16(aT2, bT[0][2], acc0, 0, 0, 0);
        acc1 = __builtin_amdgcn_mfma_f32_16x16x32_bf16(aT2, bT[1][2], acc1, 0, 0, 0);
        acc0 = __builtin_amdgcn_mfma_f32_16x16x32_bf16(aT3, bT[0][3], acc0, 0, 0, 0);
        acc1 = __builtin_amdgcn_mfma_f32_16x16x32_bf16(aT3, bT[1][3], acc1, 0, 0, 0);

        // C layout: col = lane&15, row = quad*4 + reg
        const int r0 = row0 + quad * 4;
#pragma unroll
        for (int g = 0; g < 4; ++g) {
            float v0 = acc0[g] + bias0;
            float v1 = acc1[g] + bias1;
            out[(r0 + g) * F + cb + l16] = v0;
            out[(r0 + g) * F + cb + 16 + l16] = v1;
            s0 += v0; q0 += v0 * v0;
            s1 += v1; q1 += v1 * v1;
        }
    }

    if (fuse_bn) {
        s0 += __shfl_down(s0, 32); s0 += __shfl_down(s0, 16);
        q0 += __shfl_down(q0, 32); q0 += __shfl_down(q0, 16);
        s1 += __shfl_down(s1, 32); s1 += __shfl_down(s1, 16);
        q1 += __shfl_down(q1, 32); q1 += __shfl_down(q1, 16);
        if (lane < 16) {
            unsafeAtomicAdd(&S[cb + lane], s0);
            unsafeAtomicAdd(&S2[cb + lane], q0);
            unsafeAtomicAdd(&S[cb + 16 + lane], s1);
            unsafeAtomicAdd(&S2[cb + 16 + lane], q1);
        }
    }
}

// ================= BN finalize =================
__global__ void finalize_k(const float* __restrict__ S, const float* __restrict__ S2,
        const float* __restrict__ gamma, const float* __restrict__ beta,
        float* __restrict__ scale, float* __restrict__ shift) {
    int j = threadIdx.x;  // 128 threads
    float mean = S[j] * (1.f / N_NODES);
    float var = S2[j] * (1.f / N_NODES) - mean * mean;
    float inv = rsqrtf(var + BN_EPS);
    float sc = gamma[j] * inv;
    scale[j] = sc;
    shift[j] = beta[j] - mean * sc;
}

// ================= normalize + RReLU: h (fp32) -> hb (bf16) =================
__global__ __launch_bounds__(256) void norm_act_k(const float* __restrict__ h,
        const float* __restrict__ scale, const float* __restrict__ shift,
        ushort* __restrict__ hb) {
    int i = blockIdx.x * 256 + threadIdx.x;  // one float4 per thread
    int cbase = (i & 31) * 4;
    float4 v = reinterpret_cast<const float4*>(h)[i];
    float4 sc = *reinterpret_cast<const float4*>(scale + cbase);
    float4 sh = *reinterpret_cast<const float4*>(shift + cbase);
    v.x = v.x * sc.x + sh.x;
    v.y = v.y * sc.y + sh.y;
    v.z = v.z * sc.z + sh.z;
    v.w = v.w * sc.w + sh.w;
    v.x = v.x >= 0.f ? v.x : v.x * SLOPE;
    v.y = v.y >= 0.f ? v.y : v.y * SLOPE;
    v.z = v.z >= 0.f ? v.z : v.z * SLOPE;
    v.w = v.w >= 0.f ? v.w : v.w * SLOPE;
    ushort4 o;
    o.x = f2bf(v.x); o.y = f2bf(v.y); o.z = f2bf(v.z); o.w = f2bf(v.w);
    reinterpret_cast<ushort4*>(hb)[i] = o;
}

extern "C" void kernel_launch(void* const* d_in, const int* in_sizes, int n_in,
                              void* d_out, int out_size, void* d_ws, size_t ws_size,
                              hipStream_t stream) {
    const float* x     = (const float*)d_in[0];
    const int*   ei    = (const int*)d_in[1];
    const float* ea    = (const float*)d_in[2];
    const float* W1r   = (const float*)d_in[3];
    const float* b1    = (const float*)d_in[4];
    const float* W1t   = (const float*)d_in[5];
    const float* gamma = (const float*)d_in[6];
    const float* beta  = (const float*)d_in[7];
    const float* W2r   = (const float*)d_in[8];
    const float* b2    = (const float*)d_in[9];
    const float* W2t   = (const float*)d_in[10];
    float* out = (float*)d_out;

    char* ws = (char*)d_ws;
    size_t off = 0;
    ushort* aggb  = (ushort*)(ws + off); off += (size_t)N_NODES * F * 2;      // 12.8 MB
    ushort* featb = (ushort*)(ws + off); off += (size_t)N_NODES * F * 2;      // 12.8 MB (xb, reused as hb)
    int2*   recs  = (int2*)(ws + off);   off += (size_t)N_EDGES * 8;          // 6.4 MB
    ushort* wb    = (ushort*)(ws + off); off += 4 * 16384 * 2;                // 128 KB
    int*    counts= (int*)(ws + off);    off += ((size_t)N_NODES * 4 + 255) & ~255ull;  // also cursor
    int*    offs  = (int*)(ws + off);    off += ((size_t)(N_NODES + 1) * 4 + 255) & ~255ull;
    int*    bsum  = (int*)(ws + off);    off += 256 * 4;
    float*  S     = (float*)(ws + off);  off += 128 * 4;
    float*  S2    = (float*)(ws + off);  off += 128 * 4;
    float*  scale = (float*)(ws + off);  off += 128 * 4;
    float*  shift = (float*)(ws + off);  off += 128 * 4;
    float*  h = out;  // fp32 h lives in d_out between gemm1 and norm_act

    const int* srcp = ei;
    const int* tgtp = ei + N_EDGES;

    const int egrid = (N_EDGES + 255) / 256;
    const int gath_grid = N_NODES / 4;           // 12500
    const int nf4 = N_NODES * F / 4;             // 1.6M float4s

    // ---- CSR build ----
    hipMemsetAsync(counts, 0, (size_t)N_NODES * 4, stream);
    hipMemsetAsync(S, 0, 2 * 128 * 4, stream);
    count_k<<<egrid, 256, 0, stream>>>(tgtp, counts);
    blocksum_k<<<NB, 256, 0, stream>>>(counts, bsum);
    scanb_k<<<1, 256, 0, stream>>>(bsum, NB);
    offsets_k<<<NB, 256, 0, stream>>>(counts, bsum, offs);
    hipMemcpyAsync(counts, offs, (size_t)N_NODES * 4, hipMemcpyDeviceToDevice, stream);  // counts -> cursor
    fill_k<<<egrid, 256, 0, stream>>>(srcp, tgtp, ea, counts, recs);

    // ---- casts ----
    castx_k<<<nf4 / 256, 256, 0, stream>>>(x, featb);
    castw_k<<<64, 256, 0, stream>>>(W1r, W1t, W2r, W2t, wb);

    // ---- layer 1 (+fused BN stats) ----
    gather_k<<<gath_grid, 256, 0, stream>>>(featb, offs, recs, aggb);
    gemm_mfma<<<GEMM_GRID, 256, 0, stream>>>(aggb, featb, wb, wb + 16384, b1, h, S, S2, 1);
    finalize_k<<<1, 128, 0, stream>>>(S, S2, gamma, beta, scale, shift);
    norm_act_k<<<nf4 / 256, 256, 0, stream>>>(h, scale, shift, featb);  // featb now = hb
    // ---- layer 2 ----
    gather_k<<<gath_grid, 256, 0, stream>>>(featb, offs, recs, aggb);
    gemm_mfma<<<GEMM_GRID, 256, 0, stream>>>(aggb, featb, wb + 32768, wb + 49152, b2, out,
                                             S, S2, 0);
}

// Round 4
// 305.279 us; speedup vs baseline: 9.6156x; 1.0883x over previous
//
#include <hip/hip_runtime.h>

#define N_NODES 50000
#define N_EDGES 800000
#define F 128
#define BN_EPS 1e-5f
#define SLOPE 0.22916666666666666f  // RReLU eval slope 11/48

#define NB 196            // ceil(N_NODES/256) scan blocks
#define N_RT 3125         // N_NODES/16 row-tiles (exact)
#define GEMM_GRID 512
#define CNT_BLKS 3125     // N_EDGES/256 (exact)
#define CASTX_BLKS 6250   // N_NODES*F/4/256 (exact)
#define CASTW_BLKS 64
#define REC_CAP (N_EDGES + 3 * N_NODES)  // 950000 max padded records

typedef __attribute__((ext_vector_type(8))) short bf16x8;
typedef __attribute__((ext_vector_type(4))) float f32x4;

__device__ __forceinline__ float bf2f(ushort u) {
    union { uint i; float f; } v; v.i = (uint)u << 16; return v.f;
}
__device__ __forceinline__ ushort f2bf(float f) {
    union { float f; uint i; } v; v.f = f;
    uint r = v.i + 0x7fffu + ((v.i >> 16) & 1u);  // RNE
    return (ushort)(r >> 16);
}

// ============ prep: edge-count histogram + x->bf16 + W->bf16 (fused) ============
__global__ __launch_bounds__(256) void prep_k(const int* __restrict__ tgt,
        int* __restrict__ counts, const float* __restrict__ x, ushort* __restrict__ xb,
        const float* __restrict__ W1r, const float* __restrict__ W1t,
        const float* __restrict__ W2r, const float* __restrict__ W2t,
        ushort* __restrict__ wb) {
    int b = blockIdx.x;
    if (b < CNT_BLKS) {
        int e = b * 256 + threadIdx.x;
        atomicAdd(&counts[tgt[e]], 1);
    } else if (b < CNT_BLKS + CASTX_BLKS) {
        int i = (b - CNT_BLKS) * 256 + threadIdx.x;
        float4 v = reinterpret_cast<const float4*>(x)[i];
        ushort4 o;
        o.x = f2bf(v.x); o.y = f2bf(v.y); o.z = f2bf(v.z); o.w = f2bf(v.w);
        reinterpret_cast<ushort4*>(xb)[i] = o;
    } else {
        int i = (b - CNT_BLKS - CASTX_BLKS) * 256 + threadIdx.x;  // 16384 threads
        int m = i >> 12;
        int j = i & 4095;
        const float* srcp = (m == 0) ? W1r : (m == 1) ? W1t : (m == 2) ? W2r : W2t;
        float4 v = reinterpret_cast<const float4*>(srcp)[j];
        ushort4 o;
        o.x = f2bf(v.x); o.y = f2bf(v.y); o.z = f2bf(v.z); o.w = f2bf(v.w);
        reinterpret_cast<ushort4*>(wb)[i] = o;
    }
}

// ============ scan chain (counts padded to multiples of 4 records) ============
__global__ __launch_bounds__(256) void blocksum_k(const int* __restrict__ counts,
                                                  int* __restrict__ bsum) {
    __shared__ int s[256];
    int i = blockIdx.x * 256 + threadIdx.x;
    int v = (i < N_NODES) ? ((counts[i] + 3) & ~3) : 0;
    s[threadIdx.x] = v;
    __syncthreads();
    for (int o = 128; o > 0; o >>= 1) {
        if (threadIdx.x < o) s[threadIdx.x] += s[threadIdx.x + o];
        __syncthreads();
    }
    if (threadIdx.x == 0) bsum[blockIdx.x] = s[0];
}

// exclusive scan of bsum[0..NB); also zeroes S/S2 (256 floats at Sz)
__global__ __launch_bounds__(256) void scanb_k(int* __restrict__ bsum,
                                               float* __restrict__ Sz) {
    Sz[threadIdx.x] = 0.f;
    __shared__ int s[256];
    int v = (threadIdx.x < NB) ? bsum[threadIdx.x] : 0;
    s[threadIdx.x] = v;
    __syncthreads();
    for (int o = 1; o < 256; o <<= 1) {
        int t = (threadIdx.x >= (unsigned)o) ? s[threadIdx.x - o] : 0;
        __syncthreads();
        s[threadIdx.x] += t;
        __syncthreads();
    }
    if (threadIdx.x < NB) bsum[threadIdx.x] = s[threadIdx.x] - v;  // exclusive
}

// writes offs[] and re-inits counts[] as the fill cursor (in place)
__global__ __launch_bounds__(256) void offsets_k(int* __restrict__ counts,
        const int* __restrict__ bsum, int* __restrict__ offs) {
    __shared__ int s[256];
    int i = blockIdx.x * 256 + threadIdx.x;
    int v = (i < N_NODES) ? ((counts[i] + 3) & ~3) : 0;
    s[threadIdx.x] = v;
    __syncthreads();
    for (int o = 1; o < 256; o <<= 1) {
        int t = (threadIdx.x >= (unsigned)o) ? s[threadIdx.x - o] : 0;
        __syncthreads();
        s[threadIdx.x] += t;
        __syncthreads();
    }
    int excl = s[threadIdx.x] - v + bsum[blockIdx.x];
    if (i < N_NODES) {
        offs[i] = excl;
        counts[i] = excl;  // cursor
    }
    if (i == N_NODES - 1) offs[N_NODES] = excl + v;
}

// ============ fill: 4-byte records {src:u16 | bf16(w)<<16}, target-sorted ============
__global__ __launch_bounds__(256) void fill_k(const int* __restrict__ src,
        const int* __restrict__ tgt, const float* __restrict__ ew,
        int* __restrict__ cursor, uint* __restrict__ recs) {
    int e = blockIdx.x * 256 + threadIdx.x;  // exact N_EDGES
    int p = atomicAdd(&cursor[tgt[e]], 1);
    recs[p] = (uint)(ushort)src[e] | ((uint)f2bf(ew[e]) << 16);
}

// ============ gather: aggb[n] = sum w_e * featb[src_e] (bf16 io, fp32 accum) ============
// one wave per node; records read as aligned 16B broadcasts (ranges 4-padded, filler=0)
__global__ __launch_bounds__(256) void gather_k(const ushort* __restrict__ feat,
        const int* __restrict__ offs, const uint* __restrict__ recs,
        ushort* __restrict__ agg) {
    int node = blockIdx.x * 4 + (threadIdx.x >> 6);
    int lane2 = (threadIdx.x & 63) * 2;  // bf16 element index
    int p = offs[node], end = offs[node + 1];
    float a0 = 0.f, a1 = 0.f;
    for (; p < end; p += 4) {
        uint4 r = *reinterpret_cast<const uint4*>(recs + p);  // same addr all lanes
        uint u0 = *reinterpret_cast<const uint*>(feat + (size_t)(r.x & 0xffffu) * F + lane2);
        uint u1 = *reinterpret_cast<const uint*>(feat + (size_t)(r.y & 0xffffu) * F + lane2);
        uint u2 = *reinterpret_cast<const uint*>(feat + (size_t)(r.z & 0xffffu) * F + lane2);
        uint u3 = *reinterpret_cast<const uint*>(feat + (size_t)(r.w & 0xffffu) * F + lane2);
        float w0 = bf2f((ushort)(r.x >> 16)), w1 = bf2f((ushort)(r.y >> 16));
        float w2 = bf2f((ushort)(r.z >> 16)), w3 = bf2f((ushort)(r.w >> 16));
        a0 += w0 * bf2f((ushort)u0) + w1 * bf2f((ushort)u1)
            + w2 * bf2f((ushort)u2) + w3 * bf2f((ushort)u3);
        a1 += w0 * bf2f((ushort)(u0 >> 16)) + w1 * bf2f((ushort)(u1 >> 16))
            + w2 * bf2f((ushort)(u2 >> 16)) + w3 * bf2f((ushort)(u3 >> 16));
    }
    uint o = (uint)f2bf(a0) | ((uint)f2bf(a1) << 16);
    *reinterpret_cast<uint*>(agg + (size_t)node * F + lane2) = o;
}

// ============ MFMA dual GEMM (W slices in registers, A direct from global) ============
__global__ __launch_bounds__(256) void gemm_mfma(const ushort* __restrict__ R,
        const ushort* __restrict__ T, const ushort* __restrict__ Wr,
        const ushort* __restrict__ Wt, const float* __restrict__ bias,
        float* __restrict__ out, float* __restrict__ S, float* __restrict__ S2,
        int fuse_bn) {
    const int lane = threadIdx.x & 63;
    const int wave = threadIdx.x >> 6;
    const int quad = lane >> 4;
    const int l16 = lane & 15;
    const int cb = wave * 32;

    bf16x8 bR[2][4], bT[2][4];
#pragma unroll
    for (int t = 0; t < 2; ++t)
#pragma unroll
        for (int s = 0; s < 4; ++s) {
            int col = cb + t * 16 + l16;
            int k0 = s * 32 + quad * 8;
            bR[t][s] = *reinterpret_cast<const bf16x8*>(Wr + col * F + k0);
            bT[t][s] = *reinterpret_cast<const bf16x8*>(Wt + col * F + k0);
        }
    const float bias0 = bias[cb + l16];
    const float bias1 = bias[cb + 16 + l16];

    float s0 = 0.f, q0 = 0.f, s1 = 0.f, q1 = 0.f;

    for (int rt = blockIdx.x; rt < N_RT; rt += GEMM_GRID) {
        const int row0 = rt * 16;
        const ushort* rA = R + (row0 + l16) * F + quad * 8;
        const ushort* tA = T + (row0 + l16) * F + quad * 8;
        bf16x8 aR0 = *reinterpret_cast<const bf16x8*>(rA);
        bf16x8 aR1 = *reinterpret_cast<const bf16x8*>(rA + 32);
        bf16x8 aR2 = *reinterpret_cast<const bf16x8*>(rA + 64);
        bf16x8 aR3 = *reinterpret_cast<const bf16x8*>(rA + 96);
        bf16x8 aT0 = *reinterpret_cast<const bf16x8*>(tA);
        bf16x8 aT1 = *reinterpret_cast<const bf16x8*>(tA + 32);
        bf16x8 aT2 = *reinterpret_cast<const bf16x8*>(tA + 64);
        bf16x8 aT3 = *reinterpret_cast<const bf16x8*>(tA + 96);

        f32x4 acc0 = {0.f, 0.f, 0.f, 0.f};
        f32x4 acc1 = {0.f, 0.f, 0.f, 0.f};
        acc0 = __builtin_amdgcn_mfma_f32_16x16x32_bf16(aR0, bR[0][0], acc0, 0, 0, 0);
        acc1 = __builtin_amdgcn_mfma_f32_16x16x32_bf16(aR0, bR[1][0], acc1, 0, 0, 0);
        acc0 = __builtin_amdgcn_mfma_f32_16x16x32_bf16(aR1, bR[0][1], acc0, 0, 0, 0);
        acc1 = __builtin_amdgcn_mfma_f32_16x16x32_bf16(aR1, bR[1][1], acc1, 0, 0, 0);
        acc0 = __builtin_amdgcn_mfma_f32_16x16x32_bf16(aR2, bR[0][2], acc0, 0, 0, 0);
        acc1 = __builtin_amdgcn_mfma_f32_16x16x32_bf16(aR2, bR[1][2], acc1, 0, 0, 0);
        acc0 = __builtin_amdgcn_mfma_f32_16x16x32_bf16(aR3, bR[0][3], acc0, 0, 0, 0);
        acc1 = __builtin_amdgcn_mfma_f32_16x16x32_bf16(aR3, bR[1][3], acc1, 0, 0, 0);
        acc0 = __builtin_amdgcn_mfma_f32_16x16x32_bf16(aT0, bT[0][0], acc0, 0, 0, 0);
        acc1 = __builtin_amdgcn_mfma_f32_16x16x32_bf16(aT0, bT[1][0], acc1, 0, 0, 0);
        acc0 = __builtin_amdgcn_mfma_f32_16x16x32_bf16(aT1, bT[0][1], acc0, 0, 0, 0);
        acc1 = __builtin_amdgcn_mfma_f32_16x16x32_bf16(aT1, bT[1][1], acc1, 0, 0, 0);
        acc0 = __builtin_amdgcn_mfma_f32_16x16x32_bf16(aT2, bT[0][2], acc0, 0, 0, 0);
        acc1 = __builtin_amdgcn_mfma_f32_16x16x32_bf16(aT2, bT[1][2], acc1, 0, 0, 0);
        acc0 = __builtin_amdgcn_mfma_f32_16x16x32_bf16(aT3, bT[0][3], acc0, 0, 0, 0);
        acc1 = __builtin_amdgcn_mfma_f32_16x16x32_bf16(aT3, bT[1][3], acc1, 0, 0, 0);

        const int r0 = row0 + quad * 4;  // C layout: col=lane&15, row=quad*4+reg
#pragma unroll
        for (int g = 0; g < 4; ++g) {
            float v0 = acc0[g] + bias0;
            float v1 = acc1[g] + bias1;
            out[(r0 + g) * F + cb + l16] = v0;
            out[(r0 + g) * F + cb + 16 + l16] = v1;
            s0 += v0; q0 += v0 * v0;
            s1 += v1; q1 += v1 * v1;
        }
    }

    if (fuse_bn) {
        s0 += __shfl_down(s0, 32); s0 += __shfl_down(s0, 16);
        q0 += __shfl_down(q0, 32); q0 += __shfl_down(q0, 16);
        s1 += __shfl_down(s1, 32); s1 += __shfl_down(s1, 16);
        q1 += __shfl_down(q1, 32); q1 += __shfl_down(q1, 16);
        if (lane < 16) {
            unsafeAtomicAdd(&S[cb + lane], s0);
            unsafeAtomicAdd(&S2[cb + lane], q0);
            unsafeAtomicAdd(&S[cb + 16 + lane], s1);
            unsafeAtomicAdd(&S2[cb + 16 + lane], q1);
        }
    }
}

// ============ BN finalize (inline) + RReLU: h (fp32) -> hb (bf16) ============
__global__ __launch_bounds__(256) void norm_act_k(const float* __restrict__ h,
        const float* __restrict__ S, const float* __restrict__ S2,
        const float* __restrict__ gamma, const float* __restrict__ beta,
        ushort* __restrict__ hb) {
    __shared__ float sc_s[128], sh_s[128];
    if (threadIdx.x < 128) {
        int j = threadIdx.x;
        float mean = S[j] * (1.f / N_NODES);
        float var = S2[j] * (1.f / N_NODES) - mean * mean;
        float inv = rsqrtf(var + BN_EPS);
        float sc = gamma[j] * inv;
        sc_s[j] = sc;
        sh_s[j] = beta[j] - mean * sc;
    }
    __syncthreads();
    int i = blockIdx.x * 256 + threadIdx.x;  // one float4 per thread
    int cbase = (i & 31) * 4;
    float4 v = reinterpret_cast<const float4*>(h)[i];
    float4 sc = *reinterpret_cast<const float4*>(&sc_s[cbase]);
    float4 sh = *reinterpret_cast<const float4*>(&sh_s[cbase]);
    v.x = v.x * sc.x + sh.x;
    v.y = v.y * sc.y + sh.y;
    v.z = v.z * sc.z + sh.z;
    v.w = v.w * sc.w + sh.w;
    v.x = v.x >= 0.f ? v.x : v.x * SLOPE;
    v.y = v.y >= 0.f ? v.y : v.y * SLOPE;
    v.z = v.z >= 0.f ? v.z : v.z * SLOPE;
    v.w = v.w >= 0.f ? v.w : v.w * SLOPE;
    ushort4 o;
    o.x = f2bf(v.x); o.y = f2bf(v.y); o.z = f2bf(v.z); o.w = f2bf(v.w);
    reinterpret_cast<ushort4*>(hb)[i] = o;
}

extern "C" void kernel_launch(void* const* d_in, const int* in_sizes, int n_in,
                              void* d_out, int out_size, void* d_ws, size_t ws_size,
                              hipStream_t stream) {
    const float* x     = (const float*)d_in[0];
    const int*   ei    = (const int*)d_in[1];
    const float* ea    = (const float*)d_in[2];
    const float* W1r   = (const float*)d_in[3];
    const float* b1    = (const float*)d_in[4];
    const float* W1t   = (const float*)d_in[5];
    const float* gamma = (const float*)d_in[6];
    const float* beta  = (const float*)d_in[7];
    const float* W2r   = (const float*)d_in[8];
    const float* b2    = (const float*)d_in[9];
    const float* W2t   = (const float*)d_in[10];
    float* out = (float*)d_out;

    char* ws = (char*)d_ws;
    size_t off = 0;
    ushort* aggb  = (ushort*)(ws + off); off += (size_t)N_NODES * F * 2;   // 12.8 MB
    ushort* featb = (ushort*)(ws + off); off += (size_t)N_NODES * F * 2;   // 12.8 MB (xb -> hb)
    uint*   recs  = (uint*)(ws + off);   off += (size_t)REC_CAP * 4;       // 3.8 MB
    int*    counts= (int*)(ws + off);    off += (size_t)N_NODES * 4;       // also cursor (memset with recs)
    int*    offs  = (int*)(ws + off);    off += ((size_t)(N_NODES + 1) * 4 + 255) & ~255ull;
    int*    bsum  = (int*)(ws + off);    off += 256 * 4;
    float*  S     = (float*)(ws + off);  off += 128 * 4;
    float*  S2    = (float*)(ws + off);  off += 128 * 4;   // contiguous after S (scanb zeroes both)
    ushort* wb    = (ushort*)(ws + off); off += 4 * 16384 * 2;             // 128 KB
    float*  h = out;  // fp32 h lives in d_out between gemm1 and norm_act

    const int* srcp = ei;
    const int* tgtp = ei + N_EDGES;

    // one memset covers recs (zero filler records) + counts (histogram init)
    hipMemsetAsync(recs, 0, (size_t)REC_CAP * 4 + (size_t)N_NODES * 4, stream);
    prep_k<<<CNT_BLKS + CASTX_BLKS + CASTW_BLKS, 256, 0, stream>>>(
        tgtp, counts, x, featb, W1r, W1t, W2r, W2t, wb);
    blocksum_k<<<NB, 256, 0, stream>>>(counts, bsum);
    scanb_k<<<1, 256, 0, stream>>>(bsum, S);
    offsets_k<<<NB, 256, 0, stream>>>(counts, bsum, offs);
    fill_k<<<CNT_BLKS, 256, 0, stream>>>(srcp, tgtp, ea, counts, recs);

    // ---- layer 1 (+fused BN stats) ----
    gather_k<<<N_NODES / 4, 256, 0, stream>>>(featb, offs, recs, aggb);
    gemm_mfma<<<GEMM_GRID, 256, 0, stream>>>(aggb, featb, wb, wb + 16384, b1, h, S, S2, 1);
    norm_act_k<<<CASTX_BLKS, 256, 0, stream>>>(h, S, S2, gamma, beta, featb);  // featb = hb
    // ---- layer 2 ----
    gather_k<<<N_NODES / 4, 256, 0, stream>>>(featb, offs, recs, aggb);
    gemm_mfma<<<GEMM_GRID, 256, 0, stream>>>(aggb, featb, wb + 32768, wb + 49152, b2, out,
                                             S, S2, 0);
}

// Round 5
// 285.769 us; speedup vs baseline: 10.2720x; 1.0683x over previous
//
#include <hip/hip_runtime.h>

#define N_NODES 50000
#define N_EDGES 800000
#define F 128
#define BN_EPS 1e-5f
#define SLOPE 0.22916666666666666f  // RReLU eval slope 11/48

#define NB 196            // ceil(N_NODES/256) scan blocks
#define NBKT 196          // coarse buckets (tgt>>8)
#define N_RT 3125         // N_NODES/16 row-tiles (exact)
#define GEMM_GRID 512
#define CNT_BLKS 3125     // N_EDGES/256 (exact)
#define CASTX_BLKS 6250   // N_NODES*F/4/256 (exact)
#define CASTW_BLKS 64
#define REC_CAP (N_EDGES + 3 * N_NODES)  // 950000 max padded records
#define P1_EPB 16
#define P1_CHUNK 4096
#define P1_BLKS 196       // ceil(N_EDGES/P1_CHUNK)

typedef __attribute__((ext_vector_type(8))) short bf16x8;
typedef __attribute__((ext_vector_type(4))) float f32x4;
typedef unsigned long long u64;

__device__ __forceinline__ float bf2f(ushort u) {
    union { uint i; float f; } v; v.i = (uint)u << 16; return v.f;
}
__device__ __forceinline__ ushort f2bf(float f) {
    union { float f; uint i; } v; v.f = f;
    uint r = v.i + 0x7fffu + ((v.i >> 16) & 1u);  // RNE
    return (ushort)(r >> 16);
}

// ============ prep: edge-count histogram + x->bf16 + W->bf16 (fused) ============
__global__ __launch_bounds__(256) void prep_k(const int* __restrict__ tgt,
        int* __restrict__ counts, const float* __restrict__ x, ushort* __restrict__ xb,
        const float* __restrict__ W1r, const float* __restrict__ W1t,
        const float* __restrict__ W2r, const float* __restrict__ W2t,
        ushort* __restrict__ wb) {
    int b = blockIdx.x;
    if (b < CNT_BLKS) {
        int e = b * 256 + threadIdx.x;
        atomicAdd(&counts[tgt[e]], 1);
    } else if (b < CNT_BLKS + CASTX_BLKS) {
        int i = (b - CNT_BLKS) * 256 + threadIdx.x;
        float4 v = reinterpret_cast<const float4*>(x)[i];
        ushort4 o;
        o.x = f2bf(v.x); o.y = f2bf(v.y); o.z = f2bf(v.z); o.w = f2bf(v.w);
        reinterpret_cast<ushort4*>(xb)[i] = o;
    } else {
        int i = (b - CNT_BLKS - CASTX_BLKS) * 256 + threadIdx.x;  // 16384 threads
        int m = i >> 12;
        int j = i & 4095;
        const float* srcp = (m == 0) ? W1r : (m == 1) ? W1t : (m == 2) ? W2r : W2t;
        float4 v = reinterpret_cast<const float4*>(srcp)[j];
        ushort4 o;
        o.x = f2bf(v.x); o.y = f2bf(v.y); o.z = f2bf(v.z); o.w = f2bf(v.w);
        reinterpret_cast<ushort4*>(wb)[i] = o;
    }
}

// ============ scan chain (counts padded to multiples of 4 records) ============
__global__ __launch_bounds__(256) void blocksum_k(const int* __restrict__ counts,
                                                  int* __restrict__ bsum) {
    __shared__ int s[256];
    int i = blockIdx.x * 256 + threadIdx.x;
    int v = (i < N_NODES) ? ((counts[i] + 3) & ~3) : 0;
    s[threadIdx.x] = v;
    __syncthreads();
    for (int o = 128; o > 0; o >>= 1) {
        if (threadIdx.x < o) s[threadIdx.x] += s[threadIdx.x + o];
        __syncthreads();
    }
    if (threadIdx.x == 0) bsum[blockIdx.x] = s[0];
}

// exclusive scan of bsum[0..NB); also zeroes S/S2 (256 floats at Sz)
__global__ __launch_bounds__(256) void scanb_k(int* __restrict__ bsum,
                                               float* __restrict__ Sz) {
    Sz[threadIdx.x] = 0.f;
    __shared__ int s[256];
    int v = (threadIdx.x < NB) ? bsum[threadIdx.x] : 0;
    s[threadIdx.x] = v;
    __syncthreads();
    for (int o = 1; o < 256; o <<= 1) {
        int t = (threadIdx.x >= (unsigned)o) ? s[threadIdx.x - o] : 0;
        __syncthreads();
        s[threadIdx.x] += t;
        __syncthreads();
    }
    if (threadIdx.x < NB) bsum[threadIdx.x] = s[threadIdx.x] - v;  // exclusive
}

// writes offs[] and inits bucket cursors bcur[b] = offs[b*256]
__global__ __launch_bounds__(256) void offsets_k(const int* __restrict__ counts,
        const int* __restrict__ bsum, int* __restrict__ offs, int* __restrict__ bcur) {
    __shared__ int s[256];
    int i = blockIdx.x * 256 + threadIdx.x;
    int v = (i < N_NODES) ? ((counts[i] + 3) & ~3) : 0;
    s[threadIdx.x] = v;
    __syncthreads();
    for (int o = 1; o < 256; o <<= 1) {
        int t = (threadIdx.x >= (unsigned)o) ? s[threadIdx.x - o] : 0;
        __syncthreads();
        s[threadIdx.x] += t;
        __syncthreads();
    }
    int excl = s[threadIdx.x] - v + bsum[blockIdx.x];
    if (i < N_NODES) {
        offs[i] = excl;
        if ((i & 255) == 0) bcur[i >> 8] = excl;  // bucket staging cursor
    }
    if (i == N_NODES - 1) offs[N_NODES] = excl + v;
}

// ============ sort pass 1: bin edges by coarse bucket into staging (8B recs) ============
// record: bits[0:31] = src | bf16(w)<<16 ; bits[32:63] = tgt
__global__ __launch_bounds__(256) void sort1_k(const int* __restrict__ src,
        const int* __restrict__ tgt, const float* __restrict__ ew,
        int* __restrict__ bcur, u64* __restrict__ stg) {
    __shared__ uint cnt[256];
    __shared__ uint base[256];
    __shared__ uint lcur[256];
    __shared__ uint gbase[256];
    __shared__ u64 lrec[P1_CHUNK];  // 32 KB

    const int e0 = blockIdx.x * P1_CHUNK;
    const int nE = min(P1_CHUNK, N_EDGES - e0);
    cnt[threadIdx.x] = 0;
    __syncthreads();

    u64 myrec[P1_EPB];
    bool myok[P1_EPB];
#pragma unroll
    for (int k = 0; k < P1_EPB; ++k) {
        int idx = threadIdx.x + (k << 8);
        bool ok = idx < nE;
        myok[k] = ok;
        if (ok) {
            int e = e0 + idx;
            uint t = (uint)tgt[e];
            uint lo = (uint)(ushort)src[e] | ((uint)f2bf(ew[e]) << 16);
            myrec[k] = (u64)lo | ((u64)t << 32);
            atomicAdd(&cnt[t >> 8], 1u);
        }
    }
    __syncthreads();
    // exclusive scan of cnt -> base; copy to lcur; reserve global ranges
    uint v = cnt[threadIdx.x];
    base[threadIdx.x] = v;
    __syncthreads();
    for (int o = 1; o < 256; o <<= 1) {
        uint t = (threadIdx.x >= (unsigned)o) ? base[threadIdx.x - o] : 0;
        __syncthreads();
        base[threadIdx.x] += t;
        __syncthreads();
    }
    uint excl = base[threadIdx.x] - v;
    base[threadIdx.x] = excl;
    lcur[threadIdx.x] = excl;
    if (threadIdx.x < NBKT && v > 0)
        gbase[threadIdx.x] = (uint)atomicAdd(&bcur[threadIdx.x], (int)v);
    __syncthreads();
    // place records into LDS, bucket-grouped
#pragma unroll
    for (int k = 0; k < P1_EPB; ++k) {
        if (myok[k]) {
            uint b = (uint)(myrec[k] >> 40);  // tgt>>8
            uint slot = atomicAdd(&lcur[b], 1u);
            lrec[slot] = myrec[k];
        }
    }
    __syncthreads();
    // bulk copy out: contiguous per-bucket runs
    for (int s = threadIdx.x; s < nE; s += 256) {
        u64 r = lrec[s];
        uint b = (uint)(r >> 40);
        stg[gbase[b] + ((uint)s - base[b])] = r;
    }
}

// ============ sort pass 2: one block per bucket -> final 4B recs ============
__global__ __launch_bounds__(256) void sort2_k(const int* __restrict__ offs,
        const int* __restrict__ bcur, const u64* __restrict__ stg,
        uint* __restrict__ recs) {
    __shared__ int cur[256];
    const int b = blockIdx.x;
    const int n0 = b * 256;
    int node = n0 + threadIdx.x;
    cur[threadIdx.x] = (node < N_NODES) ? offs[node] : 0;
    __syncthreads();
    const int start = offs[n0];
    const int end = bcur[b];  // post-pass-1 cursor = start + bucket edge count
    for (int i = start + threadIdx.x; i < end; i += 256) {
        u64 r = stg[i];
        int n = (int)((r >> 32) & 255u);
        int p = atomicAdd(&cur[n], 1);
        recs[p] = (uint)r;
    }
}

// ============ gather: aggb[n] = sum w_e * featb[src_e] (bf16 io, fp32 accum) ============
__global__ __launch_bounds__(256) void gather_k(const ushort* __restrict__ feat,
        const int* __restrict__ offs, const uint* __restrict__ recs,
        ushort* __restrict__ agg) {
    int node = blockIdx.x * 4 + (threadIdx.x >> 6);
    int lane2 = (threadIdx.x & 63) * 2;  // bf16 element index
    int p = offs[node], end = offs[node + 1];
    float a0 = 0.f, a1 = 0.f;
    for (; p < end; p += 4) {
        uint4 r = *reinterpret_cast<const uint4*>(recs + p);  // same addr all lanes
        uint u0 = *reinterpret_cast<const uint*>(feat + (size_t)(r.x & 0xffffu) * F + lane2);
        uint u1 = *reinterpret_cast<const uint*>(feat + (size_t)(r.y & 0xffffu) * F + lane2);
        uint u2 = *reinterpret_cast<const uint*>(feat + (size_t)(r.z & 0xffffu) * F + lane2);
        uint u3 = *reinterpret_cast<const uint*>(feat + (size_t)(r.w & 0xffffu) * F + lane2);
        float w0 = bf2f((ushort)(r.x >> 16)), w1 = bf2f((ushort)(r.y >> 16));
        float w2 = bf2f((ushort)(r.z >> 16)), w3 = bf2f((ushort)(r.w >> 16));
        a0 += w0 * bf2f((ushort)u0) + w1 * bf2f((ushort)u1)
            + w2 * bf2f((ushort)u2) + w3 * bf2f((ushort)u3);
        a1 += w0 * bf2f((ushort)(u0 >> 16)) + w1 * bf2f((ushort)(u1 >> 16))
            + w2 * bf2f((ushort)(u2 >> 16)) + w3 * bf2f((ushort)(u3 >> 16));
    }
    uint o = (uint)f2bf(a0) | ((uint)f2bf(a1) << 16);
    *reinterpret_cast<uint*>(agg + (size_t)node * F + lane2) = o;
}

// ============ MFMA dual GEMM (W in registers, A direct from global) ============
// fuse_bn=1: write bf16 h to outh + accumulate BN stats. fuse_bn=0: write fp32 to out.
__global__ __launch_bounds__(256) void gemm_mfma(const ushort* __restrict__ R,
        const ushort* __restrict__ T, const ushort* __restrict__ Wr,
        const ushort* __restrict__ Wt, const float* __restrict__ bias,
        float* __restrict__ out, ushort* __restrict__ outh,
        float* __restrict__ S, float* __restrict__ S2, int fuse_bn) {
    const int lane = threadIdx.x & 63;
    const int wave = threadIdx.x >> 6;
    const int quad = lane >> 4;
    const int l16 = lane & 15;
    const int cb = wave * 32;

    bf16x8 bR[2][4], bT[2][4];
#pragma unroll
    for (int t = 0; t < 2; ++t)
#pragma unroll
        for (int s = 0; s < 4; ++s) {
            int col = cb + t * 16 + l16;
            int k0 = s * 32 + quad * 8;
            bR[t][s] = *reinterpret_cast<const bf16x8*>(Wr + col * F + k0);
            bT[t][s] = *reinterpret_cast<const bf16x8*>(Wt + col * F + k0);
        }
    const float bias0 = bias[cb + l16];
    const float bias1 = bias[cb + 16 + l16];

    float s0 = 0.f, q0 = 0.f, s1 = 0.f, q1 = 0.f;

    for (int rt = blockIdx.x; rt < N_RT; rt += GEMM_GRID) {
        const int row0 = rt * 16;
        const ushort* rA = R + (row0 + l16) * F + quad * 8;
        const ushort* tA = T + (row0 + l16) * F + quad * 8;
        bf16x8 aR0 = *reinterpret_cast<const bf16x8*>(rA);
        bf16x8 aR1 = *reinterpret_cast<const bf16x8*>(rA + 32);
        bf16x8 aR2 = *reinterpret_cast<const bf16x8*>(rA + 64);
        bf16x8 aR3 = *reinterpret_cast<const bf16x8*>(rA + 96);
        bf16x8 aT0 = *reinterpret_cast<const bf16x8*>(tA);
        bf16x8 aT1 = *reinterpret_cast<const bf16x8*>(tA + 32);
        bf16x8 aT2 = *reinterpret_cast<const bf16x8*>(tA + 64);
        bf16x8 aT3 = *reinterpret_cast<const bf16x8*>(tA + 96);

        f32x4 acc0 = {0.f, 0.f, 0.f, 0.f};
        f32x4 acc1 = {0.f, 0.f, 0.f, 0.f};
        acc0 = __builtin_amdgcn_mfma_f32_16x16x32_bf16(aR0, bR[0][0], acc0, 0, 0, 0);
        acc1 = __builtin_amdgcn_mfma_f32_16x16x32_bf16(aR0, bR[1][0], acc1, 0, 0, 0);
        acc0 = __builtin_amdgcn_mfma_f32_16x16x32_bf16(aR1, bR[0][1], acc0, 0, 0, 0);
        acc1 = __builtin_amdgcn_mfma_f32_16x16x32_bf16(aR1, bR[1][1], acc1, 0, 0, 0);
        acc0 = __builtin_amdgcn_mfma_f32_16x16x32_bf16(aR2, bR[0][2], acc0, 0, 0, 0);
        acc1 = __builtin_amdgcn_mfma_f32_16x16x32_bf16(aR2, bR[1][2], acc1, 0, 0, 0);
        acc0 = __builtin_amdgcn_mfma_f32_16x16x32_bf16(aR3, bR[0][3], acc0, 0, 0, 0);
        acc1 = __builtin_amdgcn_mfma_f32_16x16x32_bf16(aR3, bR[1][3], acc1, 0, 0, 0);
        acc0 = __builtin_amdgcn_mfma_f32_16x16x32_bf16(aT0, bT[0][0], acc0, 0, 0, 0);
        acc1 = __builtin_amdgcn_mfma_f32_16x16x32_bf16(aT0, bT[1][0], acc1, 0, 0, 0);
        acc0 = __builtin_amdgcn_mfma_f32_16x16x32_bf16(aT1, bT[0][1], acc0, 0, 0, 0);
        acc1 = __builtin_amdgcn_mfma_f32_16x16x32_bf16(aT1, bT[1][1], acc1, 0, 0, 0);
        acc0 = __builtin_amdgcn_mfma_f32_16x16x32_bf16(aT2, bT[0][2], acc0, 0, 0, 0);
        acc1 = __builtin_amdgcn_mfma_f32_16x16x32_bf16(aT2, bT[1][2], acc1, 0, 0, 0);
        acc0 = __builtin_amdgcn_mfma_f32_16x16x32_bf16(aT3, bT[0][3], acc0, 0, 0, 0);
        acc1 = __builtin_amdgcn_mfma_f32_16x16x32_bf16(aT3, bT[1][3], acc1, 0, 0, 0);

        const int r0 = row0 + quad * 4;  // C layout: col=lane&15, row=quad*4+reg
        if (fuse_bn) {
#pragma unroll
            for (int g = 0; g < 4; ++g) {
                float v0 = acc0[g] + bias0;
                float v1 = acc1[g] + bias1;
                outh[(r0 + g) * F + cb + l16] = f2bf(v0);
                outh[(r0 + g) * F + cb + 16 + l16] = f2bf(v1);
                s0 += v0; q0 += v0 * v0;
                s1 += v1; q1 += v1 * v1;
            }
        } else {
#pragma unroll
            for (int g = 0; g < 4; ++g) {
                out[(r0 + g) * F + cb + l16] = acc0[g] + bias0;
                out[(r0 + g) * F + cb + 16 + l16] = acc1[g] + bias1;
            }
        }
    }

    if (fuse_bn) {
        s0 += __shfl_down(s0, 32); s0 += __shfl_down(s0, 16);
        q0 += __shfl_down(q0, 32); q0 += __shfl_down(q0, 16);
        s1 += __shfl_down(s1, 32); s1 += __shfl_down(s1, 16);
        q1 += __shfl_down(q1, 32); q1 += __shfl_down(q1, 16);
        if (lane < 16) {
            unsafeAtomicAdd(&S[cb + lane], s0);
            unsafeAtomicAdd(&S2[cb + lane], q0);
            unsafeAtomicAdd(&S[cb + 16 + lane], s1);
            unsafeAtomicAdd(&S2[cb + 16 + lane], q1);
        }
    }
}

// ============ BN finalize (inline) + RReLU: h (bf16) -> hb (bf16) ============
__global__ __launch_bounds__(256) void norm_act_k(const ushort* __restrict__ hraw,
        const float* __restrict__ S, const float* __restrict__ S2,
        const float* __restrict__ gamma, const float* __restrict__ beta,
        ushort* __restrict__ hb) {
    __shared__ float sc_s[128], sh_s[128];
    if (threadIdx.x < 128) {
        int j = threadIdx.x;
        float mean = S[j] * (1.f / N_NODES);
        float var = S2[j] * (1.f / N_NODES) - mean * mean;
        float inv = rsqrtf(var + BN_EPS);
        float sc = gamma[j] * inv;
        sc_s[j] = sc;
        sh_s[j] = beta[j] - mean * sc;
    }
    __syncthreads();
    int i = blockIdx.x * 256 + threadIdx.x;  // one group of 4 bf16 per thread
    int cbase = (i & 31) * 4;
    uint2 u = reinterpret_cast<const uint2*>(hraw)[i];
    float4 v = make_float4(bf2f((ushort)u.x), bf2f((ushort)(u.x >> 16)),
                           bf2f((ushort)u.y), bf2f((ushort)(u.y >> 16)));
    float4 sc = *reinterpret_cast<const float4*>(&sc_s[cbase]);
    float4 sh = *reinterpret_cast<const float4*>(&sh_s[cbase]);
    v.x = v.x * sc.x + sh.x;
    v.y = v.y * sc.y + sh.y;
    v.z = v.z * sc.z + sh.z;
    v.w = v.w * sc.w + sh.w;
    v.x = v.x >= 0.f ? v.x : v.x * SLOPE;
    v.y = v.y >= 0.f ? v.y : v.y * SLOPE;
    v.z = v.z >= 0.f ? v.z : v.z * SLOPE;
    v.w = v.w >= 0.f ? v.w : v.w * SLOPE;
    uint2 o;
    o.x = (uint)f2bf(v.x) | ((uint)f2bf(v.y) << 16);
    o.y = (uint)f2bf(v.z) | ((uint)f2bf(v.w) << 16);
    reinterpret_cast<uint2*>(hb)[i] = o;
}

extern "C" void kernel_launch(void* const* d_in, const int* in_sizes, int n_in,
                              void* d_out, int out_size, void* d_ws, size_t ws_size,
                              hipStream_t stream) {
    const float* x     = (const float*)d_in[0];
    const int*   ei    = (const int*)d_in[1];
    const float* ea    = (const float*)d_in[2];
    const float* W1r   = (const float*)d_in[3];
    const float* b1    = (const float*)d_in[4];
    const float* W1t   = (const float*)d_in[5];
    const float* gamma = (const float*)d_in[6];
    const float* beta  = (const float*)d_in[7];
    const float* W2r   = (const float*)d_in[8];
    const float* b2    = (const float*)d_in[9];
    const float* W2t   = (const float*)d_in[10];
    float* out = (float*)d_out;

    char* ws = (char*)d_ws;
    size_t off = 0;
    ushort* aggb  = (ushort*)(ws + off); off += (size_t)N_NODES * F * 2;   // 12.8 MB (aliases staging)
    ushort* featb = (ushort*)(ws + off); off += (size_t)N_NODES * F * 2;   // 12.8 MB (xb -> hb)
    uint*   recs  = (uint*)(ws + off);   off += (size_t)REC_CAP * 4;       // 3.8 MB
    int*    counts= (int*)(ws + off);    off += (size_t)N_NODES * 4;       // memset with recs
    int*    offs  = (int*)(ws + off);    off += ((size_t)(N_NODES + 1) * 4 + 255) & ~255ull;
    int*    bsum  = (int*)(ws + off);    off += 256 * 4;
    int*    bcur  = (int*)(ws + off);    off += 256 * 4;
    float*  S     = (float*)(ws + off);  off += 128 * 4;
    float*  S2    = (float*)(ws + off);  off += 128 * 4;   // contiguous after S
    ushort* wb    = (ushort*)(ws + off); off += 4 * 16384 * 2;             // 128 KB
    u64*    stg   = (u64*)aggb;          // staging aliases aggb (dead until gather)
    ushort* hraw  = (ushort*)d_out;      // bf16 h in d_out storage (gemm2 overwrites)

    const int* srcp = ei;
    const int* tgtp = ei + N_EDGES;

    // one memset covers recs (zero filler records) + counts (histogram init)
    hipMemsetAsync(recs, 0, (size_t)REC_CAP * 4 + (size_t)N_NODES * 4, stream);
    prep_k<<<CNT_BLKS + CASTX_BLKS + CASTW_BLKS, 256, 0, stream>>>(
        tgtp, counts, x, featb, W1r, W1t, W2r, W2t, wb);
    blocksum_k<<<NB, 256, 0, stream>>>(counts, bsum);
    scanb_k<<<1, 256, 0, stream>>>(bsum, S);
    offsets_k<<<NB, 256, 0, stream>>>(counts, bsum, offs, bcur);
    sort1_k<<<P1_BLKS, 256, 0, stream>>>(srcp, tgtp, ea, bcur, stg);
    sort2_k<<<NBKT, 256, 0, stream>>>(offs, bcur, stg, recs);

    // ---- layer 1 (+fused BN stats, bf16 h into d_out storage) ----
    gather_k<<<N_NODES / 4, 256, 0, stream>>>(featb, offs, recs, aggb);
    gemm_mfma<<<GEMM_GRID, 256, 0, stream>>>(aggb, featb, wb, wb + 16384, b1,
                                             out, hraw, S, S2, 1);
    norm_act_k<<<CASTX_BLKS, 256, 0, stream>>>(hraw, S, S2, gamma, beta, featb);
    // ---- layer 2 ----
    gather_k<<<N_NODES / 4, 256, 0, stream>>>(featb, offs, recs, aggb);
    gemm_mfma<<<GEMM_GRID, 256, 0, stream>>>(aggb, featb, wb + 32768, wb + 49152, b2,
                                             out, hraw, S, S2, 0);
}

// Round 6
// 248.484 us; speedup vs baseline: 11.8134x; 1.1501x over previous
//
#include <hip/hip_runtime.h>

#define N_NODES 50000
#define N_EDGES 800000
#define F 128
#define BN_EPS 1e-5f
#define SLOPE 0.22916666666666666f  // RReLU eval slope 11/48

#define NBKT 196          // coarse buckets (tgt>>8)
#define BKT_CAP 8192      // staging slots per bucket (mean 4096, sigma 64)
#define P1_CHUNK 4096
#define P1_EPB 16
#define P1_BLKS 196       // ceil(N_EDGES/P1_CHUNK)
#define CASTX_BLKS 6250   // N_NODES*F/4/256 (exact)
#define CASTW_BLKS 64
#define REC_CAP 1152608   // 800000 + 196*(1792+7), rounded up
#define N_TILES 3125      // N_NODES/16
#define GG_GRID 1024

typedef __attribute__((ext_vector_type(8))) short bf16x8;
typedef __attribute__((ext_vector_type(4))) float f32x4;
typedef unsigned long long u64;

__device__ __forceinline__ float bf2f(ushort u) {
    union { uint i; float f; } v; v.i = (uint)u << 16; return v.f;
}
__device__ __forceinline__ ushort f2bf(float f) {
    union { float f; uint i; } v; v.f = f;
    uint r = v.i + 0x7fffu + ((v.i >> 16) & 1u);  // RNE
    return (ushort)(r >> 16);
}

// ============ s1p: sort pass 1 (bucket binning) + x/W bf16 casts, one launch ============
// staging record: bits[0:31] = src | bf16(w)<<16 ; bits[32:63] = tgt
__global__ __launch_bounds__(256) void s1p_k(const int* __restrict__ src,
        const int* __restrict__ tgt, const float* __restrict__ ew,
        int* __restrict__ bcur, u64* __restrict__ stg,
        const float* __restrict__ x, ushort* __restrict__ xb,
        const float* __restrict__ W1r, const float* __restrict__ W1t,
        const float* __restrict__ W2r, const float* __restrict__ W2t,
        ushort* __restrict__ wb) {
    const int b = blockIdx.x;
    if (b >= P1_BLKS) {
        if (b < P1_BLKS + CASTX_BLKS) {
            int i = (b - P1_BLKS) * 256 + threadIdx.x;
            float4 v = reinterpret_cast<const float4*>(x)[i];
            ushort4 o;
            o.x = f2bf(v.x); o.y = f2bf(v.y); o.z = f2bf(v.z); o.w = f2bf(v.w);
            reinterpret_cast<ushort4*>(xb)[i] = o;
        } else {
            int i = (b - P1_BLKS - CASTX_BLKS) * 256 + threadIdx.x;  // 16384 total
            int m = i >> 12;
            int j = i & 4095;
            const float* sp = (m == 0) ? W1r : (m == 1) ? W1t : (m == 2) ? W2r : W2t;
            float4 v = reinterpret_cast<const float4*>(sp)[j];
            ushort4 o;
            o.x = f2bf(v.x); o.y = f2bf(v.y); o.z = f2bf(v.z); o.w = f2bf(v.w);
            reinterpret_cast<ushort4*>(wb)[i] = o;
        }
        return;
    }
    // ---- sort pass 1 ----
    __shared__ uint cnt[256];
    __shared__ uint base[256];
    __shared__ uint lcur[256];
    __shared__ uint gbase[256];
    __shared__ u64 lrec[P1_CHUNK];  // 32 KB

    const int e0 = b * P1_CHUNK;
    const int nE = min(P1_CHUNK, N_EDGES - e0);
    cnt[threadIdx.x] = 0;
    __syncthreads();

    u64 myrec[P1_EPB];
    bool myok[P1_EPB];
#pragma unroll
    for (int k = 0; k < P1_EPB; ++k) {
        int idx = threadIdx.x + (k << 8);
        bool ok = idx < nE;
        myok[k] = ok;
        if (ok) {
            int e = e0 + idx;
            uint t = (uint)tgt[e];
            uint lo = (uint)(ushort)src[e] | ((uint)f2bf(ew[e]) << 16);
            myrec[k] = (u64)lo | ((u64)t << 32);
            atomicAdd(&cnt[t >> 8], 1u);
        }
    }
    __syncthreads();
    uint v = cnt[threadIdx.x];
    base[threadIdx.x] = v;
    __syncthreads();
    for (int o = 1; o < 256; o <<= 1) {
        uint t = (threadIdx.x >= (unsigned)o) ? base[threadIdx.x - o] : 0;
        __syncthreads();
        base[threadIdx.x] += t;
        __syncthreads();
    }
    uint excl = base[threadIdx.x] - v;
    base[threadIdx.x] = excl;
    lcur[threadIdx.x] = excl;
    if (threadIdx.x < NBKT && v > 0)
        gbase[threadIdx.x] = (uint)threadIdx.x * BKT_CAP +
                             (uint)atomicAdd(&bcur[threadIdx.x], (int)v);
    __syncthreads();
#pragma unroll
    for (int k = 0; k < P1_EPB; ++k) {
        if (myok[k]) {
            uint bb = (uint)(myrec[k] >> 40);
            uint slot = atomicAdd(&lcur[bb], 1u);
            lrec[slot] = myrec[k];
        }
    }
    __syncthreads();
    for (int s = threadIdx.x; s < nE; s += 256) {
        u64 r = lrec[s];
        uint bb = (uint)(r >> 40);
        stg[gbase[bb] + ((uint)s - base[bb])] = r;
    }
}

// ============ sort pass 2: one block per bucket -> final 4B recs + per-node ranges ====
__global__ __launch_bounds__(256) void sort2_k(const int* __restrict__ bcur,
        const u64* __restrict__ stg, uint* __restrict__ recs, int2* __restrict__ rng) {
    __shared__ int lcnt[256];
    __shared__ int lcur[256];
    __shared__ int sc[256];
    __shared__ int fbase_s;
    const int b = blockIdx.x;
    const int tid = threadIdx.x;

    // redundant per-block scan of padded bucket strides -> this bucket's final base
    int cnt_t = (tid < NBKT) ? bcur[tid] : 0;
    int stride_t = (tid < NBKT) ? (((cnt_t + 7) & ~7) + 1792) : 0;
    sc[tid] = stride_t;
    lcnt[tid] = 0;
    __syncthreads();
    for (int o = 1; o < 256; o <<= 1) {
        int t = (tid >= o) ? sc[tid - o] : 0;
        __syncthreads();
        sc[tid] += t;
        __syncthreads();
    }
    if (tid == b) fbase_s = sc[tid] - stride_t;  // exclusive
    __syncthreads();
    const int fbase = fbase_s;
    const int cnt = bcur[b];
    const u64* sb = stg + (size_t)b * BKT_CAP;

    for (int i = tid; i < cnt; i += 256)
        atomicAdd(&lcnt[(int)(sb[i] >> 32) & 255], 1);
    __syncthreads();
    int myc = lcnt[tid];
    int myp = (myc + 7) & ~7;  // pad to x8 (zero filler, memset)
    sc[tid] = myp;
    __syncthreads();
    for (int o = 1; o < 256; o <<= 1) {
        int t = (tid >= o) ? sc[tid - o] : 0;
        __syncthreads();
        sc[tid] += t;
        __syncthreads();
    }
    int excl = sc[tid] - myp;
    int node = b * 256 + tid;
    if (node < N_NODES) rng[node] = make_int2(fbase + excl, fbase + excl + myp);
    lcur[tid] = fbase + excl;
    __syncthreads();
    for (int i = tid; i < cnt; i += 256) {
        u64 r = sb[i];
        int n = (int)(r >> 32) & 255;
        int p = atomicAdd(&lcur[n], 1);
        recs[p] = (uint)r;
    }
}

// ============ fused gather + dual MFMA GEMM (+BN stats for layer 1) ============
// per 16-row tile: gather agg rows into LDS (bf16), then
// out[i][j] = bias[j] + sum_k agg[i][k]*Wr[j][k] + T[i][k]*Wt[j][k]
__global__ __launch_bounds__(256) void gg_k(const ushort* __restrict__ featb,
        const int2* __restrict__ rng, const uint* __restrict__ recs,
        const ushort* __restrict__ Wr, const ushort* __restrict__ Wt,
        const float* __restrict__ bias, float* __restrict__ out,
        ushort* __restrict__ outh, float* __restrict__ S, float* __restrict__ S2,
        int layer1) {
    __shared__ ushort As[2][16][136];  // +8 pad: conflict-spread ds_read_b128

    const int lane = threadIdx.x & 63;
    const int wave = threadIdx.x >> 6;
    const int quad = lane >> 4;
    const int l16 = lane & 15;
    const int cb = wave * 32;
    const int lane2 = lane * 2;

    bf16x8 bR[2][4], bT[2][4];
#pragma unroll
    for (int t = 0; t < 2; ++t)
#pragma unroll
        for (int s = 0; s < 4; ++s) {
            int col = cb + t * 16 + l16;
            int k0 = s * 32 + quad * 8;
            bR[t][s] = *reinterpret_cast<const bf16x8*>(Wr + col * F + k0);
            bT[t][s] = *reinterpret_cast<const bf16x8*>(Wt + col * F + k0);
        }
    const float bias0 = bias[cb + l16];
    const float bias1 = bias[cb + 16 + l16];

    float s0 = 0.f, q0 = 0.f, s1 = 0.f, q1 = 0.f;
    int dbuf = 0;

    for (int tile = blockIdx.x; tile < N_TILES; tile += GG_GRID) {
        // ---- gather phase: wave w gathers rows w*4 .. w*4+3 of this tile ----
#pragma unroll
        for (int g = 0; g < 4; ++g) {
            int node = tile * 16 + wave * 4 + g;
            int2 r = rng[node];
            float a0 = 0.f, a1 = 0.f;
            for (int p = r.x; p < r.y; p += 8) {
                uint4 ra = *reinterpret_cast<const uint4*>(recs + p);
                uint4 rb = *reinterpret_cast<const uint4*>(recs + p + 4);
                uint u0 = *reinterpret_cast<const uint*>(featb + (size_t)(ra.x & 0xffffu) * F + lane2);
                uint u1 = *reinterpret_cast<const uint*>(featb + (size_t)(ra.y & 0xffffu) * F + lane2);
                uint u2 = *reinterpret_cast<const uint*>(featb + (size_t)(ra.z & 0xffffu) * F + lane2);
                uint u3 = *reinterpret_cast<const uint*>(featb + (size_t)(ra.w & 0xffffu) * F + lane2);
                uint u4 = *reinterpret_cast<const uint*>(featb + (size_t)(rb.x & 0xffffu) * F + lane2);
                uint u5 = *reinterpret_cast<const uint*>(featb + (size_t)(rb.y & 0xffffu) * F + lane2);
                uint u6 = *reinterpret_cast<const uint*>(featb + (size_t)(rb.z & 0xffffu) * F + lane2);
                uint u7 = *reinterpret_cast<const uint*>(featb + (size_t)(rb.w & 0xffffu) * F + lane2);
                float w0 = bf2f((ushort)(ra.x >> 16)), w1 = bf2f((ushort)(ra.y >> 16));
                float w2 = bf2f((ushort)(ra.z >> 16)), w3 = bf2f((ushort)(ra.w >> 16));
                float w4 = bf2f((ushort)(rb.x >> 16)), w5 = bf2f((ushort)(rb.y >> 16));
                float w6 = bf2f((ushort)(rb.z >> 16)), w7 = bf2f((ushort)(rb.w >> 16));
                a0 += w0 * bf2f((ushort)u0) + w1 * bf2f((ushort)u1)
                    + w2 * bf2f((ushort)u2) + w3 * bf2f((ushort)u3)
                    + w4 * bf2f((ushort)u4) + w5 * bf2f((ushort)u5)
                    + w6 * bf2f((ushort)u6) + w7 * bf2f((ushort)u7);
                a1 += w0 * bf2f((ushort)(u0 >> 16)) + w1 * bf2f((ushort)(u1 >> 16))
                    + w2 * bf2f((ushort)(u2 >> 16)) + w3 * bf2f((ushort)(u3 >> 16))
                    + w4 * bf2f((ushort)(u4 >> 16)) + w5 * bf2f((ushort)(u5 >> 16))
                    + w6 * bf2f((ushort)(u6 >> 16)) + w7 * bf2f((ushort)(u7 >> 16));
            }
            *reinterpret_cast<uint*>(&As[dbuf][wave * 4 + g][lane2]) =
                (uint)f2bf(a0) | ((uint)f2bf(a1) << 16);
        }
        __syncthreads();
        // ---- MFMA phase ----
        const int row0 = tile * 16;
        bf16x8 aR0 = *reinterpret_cast<const bf16x8*>(&As[dbuf][l16][quad * 8]);
        bf16x8 aR1 = *reinterpret_cast<const bf16x8*>(&As[dbuf][l16][quad * 8 + 32]);
        bf16x8 aR2 = *reinterpret_cast<const bf16x8*>(&As[dbuf][l16][quad * 8 + 64]);
        bf16x8 aR3 = *reinterpret_cast<const bf16x8*>(&As[dbuf][l16][quad * 8 + 96]);
        const ushort* tA = featb + (size_t)(row0 + l16) * F + quad * 8;
        bf16x8 aT0 = *reinterpret_cast<const bf16x8*>(tA);
        bf16x8 aT1 = *reinterpret_cast<const bf16x8*>(tA + 32);
        bf16x8 aT2 = *reinterpret_cast<const bf16x8*>(tA + 64);
        bf16x8 aT3 = *reinterpret_cast<const bf16x8*>(tA + 96);

        f32x4 acc0 = {0.f, 0.f, 0.f, 0.f};
        f32x4 acc1 = {0.f, 0.f, 0.f, 0.f};
        acc0 = __builtin_amdgcn_mfma_f32_16x16x32_bf16(aR0, bR[0][0], acc0, 0, 0, 0);
        acc1 = __builtin_amdgcn_mfma_f32_16x16x32_bf16(aR0, bR[1][0], acc1, 0, 0, 0);
        acc0 = __builtin_amdgcn_mfma_f32_16x16x32_bf16(aR1, bR[0][1], acc0, 0, 0, 0);
        acc1 = __builtin_amdgcn_mfma_f32_16x16x32_bf16(aR1, bR[1][1], acc1, 0, 0, 0);
        acc0 = __builtin_amdgcn_mfma_f32_16x16x32_bf16(aR2, bR[0][2], acc0, 0, 0, 0);
        acc1 = __builtin_amdgcn_mfma_f32_16x16x32_bf16(aR2, bR[1][2], acc1, 0, 0, 0);
        acc0 = __builtin_amdgcn_mfma_f32_16x16x32_bf16(aR3, bR[0][3], acc0, 0, 0, 0);
        acc1 = __builtin_amdgcn_mfma_f32_16x16x32_bf16(aR3, bR[1][3], acc1, 0, 0, 0);
        acc0 = __builtin_amdgcn_mfma_f32_16x16x32_bf16(aT0, bT[0][0], acc0, 0, 0, 0);
        acc1 = __builtin_amdgcn_mfma_f32_16x16x32_bf16(aT0, bT[1][0], acc1, 0, 0, 0);
        acc0 = __builtin_amdgcn_mfma_f32_16x16x32_bf16(aT1, bT[0][1], acc0, 0, 0, 0);
        acc1 = __builtin_amdgcn_mfma_f32_16x16x32_bf16(aT1, bT[1][1], acc1, 0, 0, 0);
        acc0 = __builtin_amdgcn_mfma_f32_16x16x32_bf16(aT2, bT[0][2], acc0, 0, 0, 0);
        acc1 = __builtin_amdgcn_mfma_f32_16x16x32_bf16(aT2, bT[1][2], acc1, 0, 0, 0);
        acc0 = __builtin_amdgcn_mfma_f32_16x16x32_bf16(aT3, bT[0][3], acc0, 0, 0, 0);
        acc1 = __builtin_amdgcn_mfma_f32_16x16x32_bf16(aT3, bT[1][3], acc1, 0, 0, 0);

        const int r0 = row0 + quad * 4;  // C layout: col=lane&15, row=quad*4+reg
        if (layer1) {
#pragma unroll
            for (int g = 0; g < 4; ++g) {
                float v0 = acc0[g] + bias0;
                float v1 = acc1[g] + bias1;
                outh[(r0 + g) * F + cb + l16] = f2bf(v0);
                outh[(r0 + g) * F + cb + 16 + l16] = f2bf(v1);
                s0 += v0; q0 += v0 * v0;
                s1 += v1; q1 += v1 * v1;
            }
        } else {
#pragma unroll
            for (int g = 0; g < 4; ++g) {
                out[(r0 + g) * F + cb + l16] = acc0[g] + bias0;
                out[(r0 + g) * F + cb + 16 + l16] = acc1[g] + bias1;
            }
        }
        dbuf ^= 1;
    }

    if (layer1) {
        s0 += __shfl_down(s0, 32); s0 += __shfl_down(s0, 16);
        q0 += __shfl_down(q0, 32); q0 += __shfl_down(q0, 16);
        s1 += __shfl_down(s1, 32); s1 += __shfl_down(s1, 16);
        q1 += __shfl_down(q1, 32); q1 += __shfl_down(q1, 16);
        if (lane < 16) {
            unsafeAtomicAdd(&S[cb + lane], s0);
            unsafeAtomicAdd(&S2[cb + lane], q0);
            unsafeAtomicAdd(&S[cb + 16 + lane], s1);
            unsafeAtomicAdd(&S2[cb + 16 + lane], q1);
        }
    }
}

// ============ BN finalize (inline) + RReLU: hraw (bf16) -> hb (bf16) ============
__global__ __launch_bounds__(256) void norm_act_k(const ushort* __restrict__ hraw,
        const float* __restrict__ S, const float* __restrict__ S2,
        const float* __restrict__ gamma, const float* __restrict__ beta,
        ushort* __restrict__ hb) {
    __shared__ float sc_s[128], sh_s[128];
    if (threadIdx.x < 128) {
        int j = threadIdx.x;
        float mean = S[j] * (1.f / N_NODES);
        float var = S2[j] * (1.f / N_NODES) - mean * mean;
        float inv = rsqrtf(var + BN_EPS);
        float sc = gamma[j] * inv;
        sc_s[j] = sc;
        sh_s[j] = beta[j] - mean * sc;
    }
    __syncthreads();
    int i = blockIdx.x * 256 + threadIdx.x;  // 4 bf16 per thread
    int cbase = (i & 31) * 4;
    uint2 u = reinterpret_cast<const uint2*>(hraw)[i];
    float4 v = make_float4(bf2f((ushort)u.x), bf2f((ushort)(u.x >> 16)),
                           bf2f((ushort)u.y), bf2f((ushort)(u.y >> 16)));
    float4 sc = *reinterpret_cast<const float4*>(&sc_s[cbase]);
    float4 sh = *reinterpret_cast<const float4*>(&sh_s[cbase]);
    v.x = v.x * sc.x + sh.x;
    v.y = v.y * sc.y + sh.y;
    v.z = v.z * sc.z + sh.z;
    v.w = v.w * sc.w + sh.w;
    v.x = v.x >= 0.f ? v.x : v.x * SLOPE;
    v.y = v.y >= 0.f ? v.y : v.y * SLOPE;
    v.z = v.z >= 0.f ? v.z : v.z * SLOPE;
    v.w = v.w >= 0.f ? v.w : v.w * SLOPE;
    uint2 o;
    o.x = (uint)f2bf(v.x) | ((uint)f2bf(v.y) << 16);
    o.y = (uint)f2bf(v.z) | ((uint)f2bf(v.w) << 16);
    reinterpret_cast<uint2*>(hb)[i] = o;
}

extern "C" void kernel_launch(void* const* d_in, const int* in_sizes, int n_in,
                              void* d_out, int out_size, void* d_ws, size_t ws_size,
                              hipStream_t stream) {
    const float* x     = (const float*)d_in[0];
    const int*   ei    = (const int*)d_in[1];
    const float* ea    = (const float*)d_in[2];
    const float* W1r   = (const float*)d_in[3];
    const float* b1    = (const float*)d_in[4];
    const float* W1t   = (const float*)d_in[5];
    const float* gamma = (const float*)d_in[6];
    const float* beta  = (const float*)d_in[7];
    const float* W2r   = (const float*)d_in[8];
    const float* b2    = (const float*)d_in[9];
    const float* W2t   = (const float*)d_in[10];
    float* out = (float*)d_out;

    char* ws = (char*)d_ws;
    size_t off = 0;
    u64*    stg   = (u64*)(ws + off);    off += (size_t)NBKT * BKT_CAP * 8;  // 12.85 MB
    ushort* featb = (ushort*)(ws + off); off += (size_t)N_NODES * F * 2;     // 12.8 MB (xb -> hb)
    uint*   recs  = (uint*)(ws + off);   off += (size_t)REC_CAP * 4;         // 4.61 MB (memset 0)
    int*    bcur  = (int*)(ws + off);    off += 256 * 4;                     // memset 0
    float*  S     = (float*)(ws + off);  off += 128 * 4;                     // memset 0
    float*  S2    = (float*)(ws + off);  off += 128 * 4;                     // memset 0
    int2*   rng   = (int2*)(ws + off);   off += (size_t)N_NODES * 8;         // 400 KB
    ushort* wb    = (ushort*)(ws + off); off += 4 * 16384 * 2;               // 128 KB
    ushort* hraw  = (ushort*)d_out;      // bf16 h in d_out storage (gg2 overwrites)

    const int* srcp = ei;
    const int* tgtp = ei + N_EDGES;

    // one memset: recs (zero filler) + bcur (cursors) + S/S2 (stats accum)
    hipMemsetAsync(recs, 0, (size_t)REC_CAP * 4 + 256 * 4 + 256 * 4, stream);
    s1p_k<<<P1_BLKS + CASTX_BLKS + CASTW_BLKS, 256, 0, stream>>>(
        srcp, tgtp, ea, bcur, stg, x, featb, W1r, W1t, W2r, W2t, wb);
    sort2_k<<<NBKT, 256, 0, stream>>>(bcur, stg, recs, rng);

    // ---- layer 1: fused gather+GEMM (+BN stats), bf16 h into d_out storage ----
    gg_k<<<GG_GRID, 256, 0, stream>>>(featb, rng, recs, wb, wb + 16384, b1,
                                      out, hraw, S, S2, 1);
    norm_act_k<<<CASTX_BLKS, 256, 0, stream>>>(hraw, S, S2, gamma, beta, featb);
    // ---- layer 2: fused gather+GEMM, fp32 out ----
    gg_k<<<GG_GRID, 256, 0, stream>>>(featb, rng, recs, wb + 32768, wb + 49152, b2,
                                      out, hraw, S, S2, 0);
}